// Round 1
// baseline (200.045 us; speedup 1.0000x reference)
//
#include <hip/hip_runtime.h>

typedef _Float16 f16x8 __attribute__((ext_vector_type(8)));
typedef __attribute__((ext_vector_type(4))) float f32x4;

// fp32 -> fp16 (RNE) bit pattern
static __device__ __forceinline__ unsigned short f2h(float f) {
  return __builtin_bit_cast(unsigned short, (_Float16)f);
}

// raw v_exp_f32 (inputs bounded; fp16 margin absorbs the ~1ulp gap vs libm)
#if __has_builtin(__builtin_amdgcn_exp2f)
#define EXP2(x) __builtin_amdgcn_exp2f(x)
#else
#define EXP2(x) exp2f(x)
#endif

// async global->LDS, 16 B per lane; LDS dst = wave-uniform base + lane*16.
#define GLOAD_LDS16(gp, lp)                                          \
  __builtin_amdgcn_global_load_lds(                                  \
      (const __attribute__((address_space(1))) unsigned int*)(gp),   \
      (__attribute__((address_space(3))) unsigned int*)(lp), 16, 0, 0)

// ---------------------------------------------------------------------------
// Kernel 0: fp32 -> fp16 conversion for X, W_qkv, W_proj (one launch).
// ---------------------------------------------------------------------------
__global__ __launch_bounds__(256) void cvt_all(
    const float* __restrict__ X, const float* __restrict__ Wq,
    const float* __restrict__ Wp, unsigned short* __restrict__ Xb,
    unsigned short* __restrict__ Wqb, unsigned short* __restrict__ Wpb) {
  const int i = blockIdx.x * 256 + threadIdx.x;
  const float4* src;
  unsigned short* dst;
  int off;
  if (i < 1048576) {
    src = (const float4*)X; dst = Xb; off = i;
  } else if (i < 1835008) {
    src = (const float4*)Wq; dst = Wqb; off = i - 1048576;
  } else {
    src = (const float4*)Wp; dst = Wpb; off = i - 1835008;
  }
  const float4 v = src[off];
  *(ushort4*)(dst + (size_t)off * 4) =
      make_ushort4(f2h(v.x), f2h(v.y), f2h(v.z), f2h(v.w));
}

// ---------------------------------------------------------------------------
// Kernel 1: QKV projection.  512 threads / 8 waves (4x2 wave grid,
// acc 2x4 per wave) on the 128x128 tile, BK=32, glds dbuf (1 barrier/iter)
// + XOR column-group swizzle (measured 0 conflicts).  Staging: waves 0-3
// stage A, waves 4-7 stage B (2 granule-chunks each).  Q pre-scaled.
//   Q,K: [B,H,2048,64] fp16     V: transposed [B,H,64,2048] fp16
// ---------------------------------------------------------------------------
__global__ __launch_bounds__(512) void qkv_gemm(
    const unsigned short* __restrict__ Xb, const unsigned short* __restrict__ Wb,
    const float* __restrict__ bias, unsigned short* __restrict__ Qb,
    unsigned short* __restrict__ Kb, unsigned short* __restrict__ Vt) {
  __shared__ __align__(16) unsigned short A_sh[2][128 * 32];
  __shared__ __align__(16) unsigned short B_sh[2][128 * 32];
  const int n0 = blockIdx.x * 128, m0 = blockIdx.y * 128;
  const int tid = threadIdx.x, lane = tid & 63, wave = tid >> 6;  // 0..7
  const int wr = wave >> 1, wc = wave & 1;   // 4x2 wave grid
  const int lm = lane & 15, lg = lane >> 4;
  const int r4 = lane >> 2;                              // staging row in chunk
  const int sg8 = (((lane & 3) ^ ((r4 >> 1) & 3)) * 8);  // swizzled src colgrp
  const int lgx = (lg ^ ((lm >> 1) & 3)) * 8;            // swizzled read colgrp

  f32x4 acc[2][4] = {};

#define QSTAGE(k0_, b_)                                                       \
  do {                                                                        \
    if (wave < 4) {                                                           \
      _Pragma("unroll")                                                       \
      for (int j = 0; j < 2; ++j) {                                           \
        const int chunk = wave * 2 + j;                                       \
        const int row = chunk * 16 + r4;                                      \
        GLOAD_LDS16(Xb + (size_t)(m0 + row) * 1024 + (k0_) + sg8,             \
                    &A_sh[b_][chunk * 512]);                                  \
      }                                                                       \
    } else {                                                                  \
      _Pragma("unroll")                                                       \
      for (int j = 0; j < 2; ++j) {                                           \
        const int chunk = (wave - 4) * 2 + j;                                 \
        const int row = chunk * 16 + r4;                                      \
        GLOAD_LDS16(Wb + (size_t)(n0 + row) * 1024 + (k0_) + sg8,             \
                    &B_sh[b_][chunk * 512]);                                  \
      }                                                                       \
    }                                                                         \
  } while (0)

  QSTAGE(0, 0);

  for (int it = 0; it < 32; ++it) {
    const int cur = it & 1;
    __syncthreads();  // buf[cur] ready; buf[cur^1] free
    if (it < 31) QSTAGE((it + 1) * 32, cur ^ 1);  // fly during compute

    f16x8 af[2], bfr[4];
#pragma unroll
    for (int mi = 0; mi < 2; ++mi)
      af[mi] = *(const f16x8*)&A_sh[cur][(wr * 32 + mi * 16 + lm) * 32 + lgx];
#pragma unroll
    for (int ni = 0; ni < 4; ++ni)
      bfr[ni] = *(const f16x8*)&B_sh[cur][(wc * 64 + ni * 16 + lm) * 32 + lgx];
#pragma unroll
    for (int mi = 0; mi < 2; ++mi)
#pragma unroll
      for (int ni = 0; ni < 4; ++ni)
        acc[mi][ni] = __builtin_amdgcn_mfma_f32_16x16x32_f16(
            af[mi], bfr[ni], acc[mi][ni], 0, 0, 0);
  }
#undef QSTAGE

  const float qscale = 0.18033688011112042f;  // log2(e)/8  (folded attn scale)
#pragma unroll
  for (int mi = 0; mi < 2; ++mi) {
#pragma unroll
    for (int ni = 0; ni < 4; ++ni) {
      const int gn = n0 + wc * 64 + ni * 16 + lm;
      const float bv = bias[gn];
      const int which = gn >> 10;
      const int h = (gn >> 6) & 15;
      const int hd = gn & 63;
      float v[4];
#pragma unroll
      for (int r = 0; r < 4; ++r) v[r] = acc[mi][ni][r] + bv;
      const int gm0 = m0 + wr * 32 + mi * 16 + lg * 4;
      const int bb = gm0 >> 11;
      const int nq0 = gm0 & 2047;
      if (which == 0) {
        unsigned short* p = Qb + (((size_t)bb * 16 + h) * 2048 + nq0) * 64 + hd;
        p[0] = f2h(v[0] * qscale);   p[64] = f2h(v[1] * qscale);
        p[128] = f2h(v[2] * qscale); p[192] = f2h(v[3] * qscale);
      } else if (which == 1) {
        unsigned short* p = Kb + (((size_t)bb * 16 + h) * 2048 + nq0) * 64 + hd;
        p[0] = f2h(v[0]);   p[64] = f2h(v[1]);
        p[128] = f2h(v[2]); p[192] = f2h(v[3]);
      } else {
        *(ushort4*)(Vt + (((size_t)bb * 16 + h) * 64 + hd) * 2048 + nq0) =
            make_ushort4(f2h(v[0]), f2h(v[1]), f2h(v[2]), f2h(v[3]));
      }
    }
  }
}

// ---------------------------------------------------------------------------
// Kernel 2: flash attention, restructured for LDS-BW: 4 waves x 32 q-rows
// (256 thr), grid (16,32).  Each wave reads the K/V tile ONCE and amortizes
// it over 2x the q-rows (kf/vb fragments reused across mi) -> per-q LDS
// traffic 1.375KB -> 0.875KB.  P_sh is kc-phased [128][36] (write/consume
// one 32-kv half at a time; wave-local, no extra barriers).  Same staging
// granules + XOR swizzle as before (4 GLOADs/wave now).  setprio around
// MFMA clusters (T5).
// ---------------------------------------------------------------------------
__global__ __launch_bounds__(256) void attn_kernel(
    const unsigned short* __restrict__ Qb, const unsigned short* __restrict__ Kb,
    const unsigned short* __restrict__ Vt, unsigned short* __restrict__ Ob) {
  __shared__ __align__(16) unsigned short K_sh[2][2][64 * 32];
  __shared__ __align__(16) unsigned short V_sh[2][2][64 * 32];
  __shared__ __align__(16) unsigned short P_sh[128 * 36];
  const int bh = blockIdx.y, q0 = blockIdx.x * 128;
  const size_t base = (size_t)bh * (2048 * 64);
  const unsigned short* Qp = Qb + base;
  const unsigned short* Kp = Kb + base;
  const unsigned short* Vp = Vt + base;  // [64][2048]
  const int tid = threadIdx.x, lane = tid & 63, wave = tid >> 6;  // 0..3
  const int lm = lane & 15, lg = lane >> 4;
  const int r4 = lane >> 2;
  const int sg8 = (((lane & 3) ^ ((r4 >> 1) & 3)) * 8);
  const int lgx = (lg ^ ((lm >> 1) & 3)) * 8;

  f16x8 qf[2][2];
#pragma unroll
  for (int mi = 0; mi < 2; ++mi)
#pragma unroll
    for (int kc = 0; kc < 2; ++kc)
      qf[mi][kc] = *(const f16x8*)(Qp +
          (size_t)(q0 + wave * 32 + mi * 16 + lm) * 64 + kc * 32 + lg * 8);

  f32x4 o[2][4] = {};
  float lsum[2][4] = {};

  const bool isV = wave >= 2;
  const int plane = wave & 1;

#define STAGE(kt_, b_)                                                        \
  do {                                                                        \
    if (!isV) {                                                               \
      _Pragma("unroll")                                                       \
      for (int c = 0; c < 4; ++c)                                             \
        GLOAD_LDS16(Kp + (size_t)((kt_) * 64 + c * 16 + r4) * 64 +            \
                        plane * 32 + sg8,                                     \
                    &K_sh[b_][plane][c * 512]);                               \
    } else {                                                                  \
      _Pragma("unroll")                                                       \
      for (int c = 0; c < 4; ++c)                                             \
        GLOAD_LDS16(Vp + (size_t)(c * 16 + r4) * 2048 +                       \
                        (kt_) * 64 + plane * 32 + sg8,                        \
                    &V_sh[b_][plane][c * 512]);                               \
    }                                                                         \
  } while (0)

  STAGE(0, 0);

  for (int kt = 0; kt < 32; ++kt) {
    const int cur = kt & 1;
    __syncthreads();
    if (kt < 31) STAGE(kt + 1, cur ^ 1);

    // ---- QK^T: load 8 kf fragments once, reuse across both mi ----
    f16x8 kfr[2][4];
#pragma unroll
    for (int kc = 0; kc < 2; ++kc)
#pragma unroll
      for (int ni = 0; ni < 4; ++ni)
        kfr[kc][ni] =
            *(const f16x8*)&K_sh[cur][kc][(ni * 16 + lm) * 32 + lgx];

    f32x4 s[2][4] = {};
    __builtin_amdgcn_s_setprio(1);
#pragma unroll
    for (int kc = 0; kc < 2; ++kc)
#pragma unroll
      for (int ni = 0; ni < 4; ++ni) {
        s[0][ni] = __builtin_amdgcn_mfma_f32_16x16x32_f16(
            qf[0][kc], kfr[kc][ni], s[0][ni], 0, 0, 0);
        s[1][ni] = __builtin_amdgcn_mfma_f32_16x16x32_f16(
            qf[1][kc], kfr[kc][ni], s[1][ni], 0, 0, 0);
      }
    __builtin_amdgcn_s_setprio(0);

    // ---- softmax + PV, kc-phased over the two 32-kv halves ----
#pragma unroll
    for (int ph = 0; ph < 2; ++ph) {
#pragma unroll
      for (int mi = 0; mi < 2; ++mi)
#pragma unroll
        for (int nn = 0; nn < 2; ++nn) {
          const f32x4 sv = s[mi][ph * 2 + nn];
          float e0 = EXP2(sv[0]), e1 = EXP2(sv[1]);
          float e2 = EXP2(sv[2]), e3 = EXP2(sv[3]);
          lsum[mi][0] += e0; lsum[mi][1] += e1;
          lsum[mi][2] += e2; lsum[mi][3] += e3;
          unsigned short* pp =
              &P_sh[(wave * 32 + mi * 16 + lg * 4) * 36 + nn * 16 + lm];
          pp[0] = f2h(e0);   pp[36] = f2h(e1);
          pp[72] = f2h(e2);  pp[108] = f2h(e3);
        }

      f16x8 pa[2], vbr[4];
#pragma unroll
      for (int mi = 0; mi < 2; ++mi)
        pa[mi] =
            *(const f16x8*)&P_sh[(wave * 32 + mi * 16 + lm) * 36 + lg * 8];
#pragma unroll
      for (int ni = 0; ni < 4; ++ni)
        vbr[ni] =
            *(const f16x8*)&V_sh[cur][ph][(ni * 16 + lm) * 32 + lgx];
      __builtin_amdgcn_s_setprio(1);
#pragma unroll
      for (int ni = 0; ni < 4; ++ni) {
        o[0][ni] = __builtin_amdgcn_mfma_f32_16x16x32_f16(
            pa[0], vbr[ni], o[0][ni], 0, 0, 0);
        o[1][ni] = __builtin_amdgcn_mfma_f32_16x16x32_f16(
            pa[1], vbr[ni], o[1][ni], 0, 0, 0);
      }
      __builtin_amdgcn_s_setprio(0);
    }
  }
#undef STAGE

  const int b = bh >> 4, h = bh & 15;
#pragma unroll
  for (int mi = 0; mi < 2; ++mi)
#pragma unroll
    for (int r = 0; r < 4; ++r) {
      float l = lsum[mi][r];
      l += __shfl_xor(l, 1);
      l += __shfl_xor(l, 2);
      l += __shfl_xor(l, 4);
      l += __shfl_xor(l, 8);
      const float inv = 1.0f / l;
      const int nq = q0 + wave * 32 + mi * 16 + lg * 4 + r;
      unsigned short* p = Ob + ((size_t)(b * 2048 + nq) * 16 + h) * 64 + lm;
      p[0] = f2h(o[mi][0][r] * inv);
      p[16] = f2h(o[mi][1][r] * inv);
      p[32] = f2h(o[mi][2][r] * inv);
      p[48] = f2h(o[mi][3][r] * inv);
    }
}

// ---------------------------------------------------------------------------
// Kernel 3: output projection, BK=32, 64x128 tile, fp16 MFMA.
// (round-10 version: dbuf async staging + XOR swizzle)
// ---------------------------------------------------------------------------
__global__ __launch_bounds__(256) void proj_gemm(
    const unsigned short* __restrict__ A, const unsigned short* __restrict__ Wb,
    const float* __restrict__ bias, float* __restrict__ Out) {
  __shared__ __align__(16) unsigned short A_sh[2][64 * 32];
  __shared__ __align__(16) unsigned short B_sh[2][128 * 32];
  const int n0 = blockIdx.x * 128, m0 = blockIdx.y * 64;
  const int tid = threadIdx.x, lane = tid & 63, wave = tid >> 6;
  const int wr = wave >> 1, wc = wave & 1, lm = lane & 15, lg = lane >> 4;
  const int r4 = lane >> 2;
  const int sg8 = (((lane & 3) ^ ((r4 >> 1) & 3)) * 8);
  const int lgx = (lg ^ ((lm >> 1) & 3)) * 8;

  f32x4 acc[2][4] = {};

#define PSTAGE(k0_, b_)                                                       \
  do {                                                                        \
    {                                                                         \
      const int row = wave * 16 + r4;                                         \
      GLOAD_LDS16(A + (size_t)(m0 + row) * 1024 + (k0_) + sg8,                \
                  &A_sh[b_][wave * 512]);                                     \
    }                                                                         \
    _Pragma("unroll")                                                         \
    for (int j = 0; j < 2; ++j) {                                             \
      const int chunk = wave * 2 + j;                                         \
      const int row = chunk * 16 + r4;                                        \
      GLOAD_LDS16(Wb + (size_t)(n0 + row) * 1024 + (k0_) + sg8,               \
                  &B_sh[b_][chunk * 512]);                                    \
    }                                                                         \
  } while (0)

  PSTAGE(0, 0);

  for (int it = 0; it < 32; ++it) {
    const int cur = it & 1;
    __syncthreads();
    if (it < 31) PSTAGE((it + 1) * 32, cur ^ 1);

    f16x8 af[2], bfr[4];
#pragma unroll
    for (int mi = 0; mi < 2; ++mi)
      af[mi] = *(const f16x8*)&A_sh[cur][(wr * 32 + mi * 16 + lm) * 32 + lgx];
#pragma unroll
    for (int ni = 0; ni < 4; ++ni)
      bfr[ni] = *(const f16x8*)&B_sh[cur][(wc * 64 + ni * 16 + lm) * 32 + lgx];
#pragma unroll
    for (int mi = 0; mi < 2; ++mi)
#pragma unroll
      for (int ni = 0; ni < 4; ++ni)
        acc[mi][ni] = __builtin_amdgcn_mfma_f32_16x16x32_f16(
            af[mi], bfr[ni], acc[mi][ni], 0, 0, 0);
  }
#undef PSTAGE

#pragma unroll
  for (int mi = 0; mi < 2; ++mi)
#pragma unroll
    for (int ni = 0; ni < 4; ++ni) {
      const int gn = n0 + wc * 64 + ni * 16 + lm;
      const float bv = bias[gn];
#pragma unroll
      for (int r = 0; r < 4; ++r) {
        const int gm = m0 + wr * 32 + mi * 16 + lg * 4 + r;
        Out[(size_t)gm * 1024 + gn] = acc[mi][ni][r] + bv;
      }
    }
}

extern "C" void kernel_launch(void* const* d_in, const int* in_sizes, int n_in,
                              void* d_out, int out_size, void* d_ws, size_t ws_size,
                              hipStream_t stream) {
  const float* x      = (const float*)d_in[0];
  const float* W_qkv  = (const float*)d_in[1];
  const float* b_qkv  = (const float*)d_in[2];
  const float* W_proj = (const float*)d_in[3];
  const float* b_proj = (const float*)d_in[4];
  float* out = (float*)d_out;

  unsigned short* Qb  = (unsigned short*)d_ws;
  unsigned short* Kb  = Qb + 4194304;
  unsigned short* Vt  = Kb + 4194304;
  unsigned short* Ao  = Vt + 4194304;
  unsigned short* Xb  = Ao + 4194304;
  unsigned short* Wqb = Xb + 4194304;
  unsigned short* Wpb = Wqb + 3145728;

  cvt_all<<<8192, 256, 0, stream>>>(x, W_qkv, W_proj, Xb, Wqb, Wpb);
  qkv_gemm<<<dim3(24, 32), 512, 0, stream>>>(Xb, Wqb, b_qkv, Qb, Kb, Vt);
  attn_kernel<<<dim3(16, 32), 256, 0, stream>>>(Qb, Kb, Vt, Ao);
  proj_gemm<<<dim3(8, 64), 256, 0, stream>>>(Ao, Wpb, b_proj, out);
}

// Round 2
// 194.385 us; speedup vs baseline: 1.0291x; 1.0291x over previous
//
#include <hip/hip_runtime.h>

typedef _Float16 f16x8 __attribute__((ext_vector_type(8)));
typedef __attribute__((ext_vector_type(4))) float f32x4;

// fp32 -> fp16 (RNE) bit pattern
static __device__ __forceinline__ unsigned short f2h(float f) {
  return __builtin_bit_cast(unsigned short, (_Float16)f);
}

// raw v_exp_f32 (inputs bounded; fp16 margin absorbs the ~1ulp gap vs libm)
#if __has_builtin(__builtin_amdgcn_exp2f)
#define EXP2(x) __builtin_amdgcn_exp2f(x)
#else
#define EXP2(x) exp2f(x)
#endif

// async global->LDS, 16 B per lane; LDS dst = wave-uniform base + lane*16.
#define GLOAD_LDS16(gp, lp)                                          \
  __builtin_amdgcn_global_load_lds(                                  \
      (const __attribute__((address_space(1))) unsigned int*)(gp),   \
      (__attribute__((address_space(3))) unsigned int*)(lp), 16, 0, 0)

// ---------------------------------------------------------------------------
// Kernel 0: fp32 -> fp16 conversion for X, W_qkv, W_proj (one launch).
// ---------------------------------------------------------------------------
__global__ __launch_bounds__(256) void cvt_all(
    const float* __restrict__ X, const float* __restrict__ Wq,
    const float* __restrict__ Wp, unsigned short* __restrict__ Xb,
    unsigned short* __restrict__ Wqb, unsigned short* __restrict__ Wpb) {
  const int i = blockIdx.x * 256 + threadIdx.x;
  const float4* src;
  unsigned short* dst;
  int off;
  if (i < 1048576) {
    src = (const float4*)X; dst = Xb; off = i;
  } else if (i < 1835008) {
    src = (const float4*)Wq; dst = Wqb; off = i - 1048576;
  } else {
    src = (const float4*)Wp; dst = Wpb; off = i - 1835008;
  }
  const float4 v = src[off];
  *(ushort4*)(dst + (size_t)off * 4) =
      make_ushort4(f2h(v.x), f2h(v.y), f2h(v.z), f2h(v.w));
}

// ---------------------------------------------------------------------------
// Kernel 1: QKV projection.  NEW this round: 256 threads / 4 waves (2x2 wave
// grid), each wave owns a 64x64 sub-tile (acc[4][4]) of the 128x128 tile.
// Rationale: LDS-issue-bound before (6 ds_read_b128 per 8 MFMA); now 8 reads
// feed 16 MFMA (ratio 0.75 -> 0.5), per-CU LDS cycles/iter 1728 -> 1152,
// 2x MFMA per barrier, 16 independent acc chains.  BK=32, glds dbuf
// (1 barrier/iter) + XOR column-group swizzle.  Each wave stages 2 A-chunks
// + 2 B-chunks (4 GLOADs).  Q pre-scaled by log2(e)/8.
//   Q,K: [B,H,2048,64] fp16     V: transposed [B,H,64,2048] fp16
// ---------------------------------------------------------------------------
__global__ __launch_bounds__(256, 3) void qkv_gemm(
    const unsigned short* __restrict__ Xb, const unsigned short* __restrict__ Wb,
    const float* __restrict__ bias, unsigned short* __restrict__ Qb,
    unsigned short* __restrict__ Kb, unsigned short* __restrict__ Vt) {
  __shared__ __align__(16) unsigned short A_sh[2][128 * 32];
  __shared__ __align__(16) unsigned short B_sh[2][128 * 32];
  const int n0 = blockIdx.x * 128, m0 = blockIdx.y * 128;
  const int tid = threadIdx.x, lane = tid & 63, wave = tid >> 6;  // 0..3
  const int wr = wave >> 1, wc = wave & 1;   // 2x2 wave grid, 64x64 each
  const int lm = lane & 15, lg = lane >> 4;
  const int r4 = lane >> 2;                              // staging row in chunk
  const int sg8 = (((lane & 3) ^ ((r4 >> 1) & 3)) * 8);  // swizzled src colgrp
  const int lgx = (lg ^ ((lm >> 1) & 3)) * 8;            // swizzled read colgrp

  f32x4 acc[4][4] = {};

#define QSTAGE(k0_, b_)                                                       \
  do {                                                                        \
    _Pragma("unroll")                                                         \
    for (int j = 0; j < 2; ++j) {                                             \
      const int chunk = wave * 2 + j;                                         \
      const int row = chunk * 16 + r4;                                        \
      GLOAD_LDS16(Xb + (size_t)(m0 + row) * 1024 + (k0_) + sg8,               \
                  &A_sh[b_][chunk * 512]);                                    \
      GLOAD_LDS16(Wb + (size_t)(n0 + row) * 1024 + (k0_) + sg8,               \
                  &B_sh[b_][chunk * 512]);                                    \
    }                                                                         \
  } while (0)

  QSTAGE(0, 0);

  for (int it = 0; it < 32; ++it) {
    const int cur = it & 1;
    __syncthreads();  // buf[cur] ready; buf[cur^1] free
    if (it < 31) QSTAGE((it + 1) * 32, cur ^ 1);  // fly during compute

    f16x8 af[4], bfr[4];
#pragma unroll
    for (int mi = 0; mi < 4; ++mi)
      af[mi] = *(const f16x8*)&A_sh[cur][(wr * 64 + mi * 16 + lm) * 32 + lgx];
#pragma unroll
    for (int ni = 0; ni < 4; ++ni)
      bfr[ni] = *(const f16x8*)&B_sh[cur][(wc * 64 + ni * 16 + lm) * 32 + lgx];
    __builtin_amdgcn_s_setprio(1);
#pragma unroll
    for (int mi = 0; mi < 4; ++mi)
#pragma unroll
      for (int ni = 0; ni < 4; ++ni)
        acc[mi][ni] = __builtin_amdgcn_mfma_f32_16x16x32_f16(
            af[mi], bfr[ni], acc[mi][ni], 0, 0, 0);
    __builtin_amdgcn_s_setprio(0);
  }
#undef QSTAGE

  const float qscale = 0.18033688011112042f;  // log2(e)/8  (folded attn scale)
#pragma unroll
  for (int mi = 0; mi < 4; ++mi) {
#pragma unroll
    for (int ni = 0; ni < 4; ++ni) {
      const int gn = n0 + wc * 64 + ni * 16 + lm;
      const float bv = bias[gn];
      const int which = gn >> 10;
      const int h = (gn >> 6) & 15;
      const int hd = gn & 63;
      float v[4];
#pragma unroll
      for (int r = 0; r < 4; ++r) v[r] = acc[mi][ni][r] + bv;
      const int gm0 = m0 + wr * 64 + mi * 16 + lg * 4;
      const int bb = gm0 >> 11;
      const int nq0 = gm0 & 2047;
      if (which == 0) {
        unsigned short* p = Qb + (((size_t)bb * 16 + h) * 2048 + nq0) * 64 + hd;
        p[0] = f2h(v[0] * qscale);   p[64] = f2h(v[1] * qscale);
        p[128] = f2h(v[2] * qscale); p[192] = f2h(v[3] * qscale);
      } else if (which == 1) {
        unsigned short* p = Kb + (((size_t)bb * 16 + h) * 2048 + nq0) * 64 + hd;
        p[0] = f2h(v[0]);   p[64] = f2h(v[1]);
        p[128] = f2h(v[2]); p[192] = f2h(v[3]);
      } else {
        *(ushort4*)(Vt + (((size_t)bb * 16 + h) * 64 + hd) * 2048 + nq0) =
            make_ushort4(f2h(v[0]), f2h(v[1]), f2h(v[2]), f2h(v[3]));
      }
    }
  }
}

// ---------------------------------------------------------------------------
// Kernel 2: flash attention (round-9 best, byte-identical revert).  128
// q-rows, 8 waves x 16 rows (512 thr); grid (16,32).  Async dbuf, 1
// barrier/tile; K/V planes [kc][64][32] + XOR swizzle (0 conflicts); P_sh
// stride 68.  LDS-issue-bound at 16 waves/CU (measured: 62.5 us).
// ---------------------------------------------------------------------------
__global__ __launch_bounds__(512) void attn_kernel(
    const unsigned short* __restrict__ Qb, const unsigned short* __restrict__ Kb,
    const unsigned short* __restrict__ Vt, unsigned short* __restrict__ Ob) {
  __shared__ __align__(16) unsigned short K_sh[2][2][64 * 32];
  __shared__ __align__(16) unsigned short V_sh[2][2][64 * 32];
  __shared__ __align__(16) unsigned short P_sh[128 * 68];
  const int bh = blockIdx.y, q0 = blockIdx.x * 128;
  const size_t base = (size_t)bh * (2048 * 64);
  const unsigned short* Qp = Qb + base;
  const unsigned short* Kp = Kb + base;
  const unsigned short* Vp = Vt + base;  // [64][2048]
  const int tid = threadIdx.x, lane = tid & 63, wave = tid >> 6;  // 0..7
  const int lm = lane & 15, lg = lane >> 4;
  const int r4 = lane >> 2;
  const int sg8 = (((lane & 3) ^ ((r4 >> 1) & 3)) * 8);
  const int lgx = (lg ^ ((lm >> 1) & 3)) * 8;

  f16x8 qf[2];
#pragma unroll
  for (int kc = 0; kc < 2; ++kc)
    qf[kc] = *(const f16x8*)(Qp +
        (size_t)(q0 + wave * 16 + lm) * 64 + kc * 32 + lg * 8);

  f32x4 o[4] = {};
  float lsum[4] = {};

  const bool isV = wave >= 4;
  const int plane = wave & 1;
  const int half = (wave >> 1) & 1;

#define STAGE(kt_, b_)                                                        \
  do {                                                                        \
    if (!isV) {                                                               \
      _Pragma("unroll")                                                       \
      for (int qv = 0; qv < 2; ++qv)                                          \
        GLOAD_LDS16(Kp + (size_t)((kt_) * 64 + half * 32 + qv * 16 + r4) * 64 \
                        + plane * 32 + sg8,                                   \
                    &K_sh[b_][plane][(half * 2 + qv) * 512]);                 \
    } else {                                                                  \
      _Pragma("unroll")                                                       \
      for (int qv = 0; qv < 2; ++qv)                                          \
        GLOAD_LDS16(Vp + (size_t)(half * 32 + qv * 16 + r4) * 2048 +          \
                        (kt_) * 64 + plane * 32 + sg8,                        \
                    &V_sh[b_][plane][(half * 2 + qv) * 512]);                 \
    }                                                                         \
  } while (0)

  STAGE(0, 0);

  for (int kt = 0; kt < 32; ++kt) {
    const int cur = kt & 1;
    __syncthreads();
    if (kt < 31) STAGE(kt + 1, cur ^ 1);

    f32x4 s[4] = {};
#pragma unroll
    for (int kc = 0; kc < 2; ++kc) {
#pragma unroll
      for (int ni = 0; ni < 4; ++ni) {
        const f16x8 kf =
            *(const f16x8*)&K_sh[cur][kc][(ni * 16 + lm) * 32 + lgx];
        s[ni] = __builtin_amdgcn_mfma_f32_16x16x32_f16(qf[kc], kf, s[ni], 0, 0, 0);
      }
    }

#pragma unroll
    for (int ni = 0; ni < 4; ++ni) {
      float p0 = EXP2(s[ni][0]), p1 = EXP2(s[ni][1]);
      float p2 = EXP2(s[ni][2]), p3 = EXP2(s[ni][3]);
      lsum[0] += p0; lsum[1] += p1; lsum[2] += p2; lsum[3] += p3;
      unsigned short* pp = &P_sh[(wave * 16 + lg * 4) * 68 + ni * 16 + lm];
      pp[0] = f2h(p0);    pp[68] = f2h(p1);
      pp[136] = f2h(p2);  pp[204] = f2h(p3);
    }

#pragma unroll
    for (int kc = 0; kc < 2; ++kc) {
      const f16x8 pa =
          *(const f16x8*)&P_sh[(wave * 16 + lm) * 68 + kc * 32 + lg * 8];
#pragma unroll
      for (int ni = 0; ni < 4; ++ni) {
        const f16x8 vb =
            *(const f16x8*)&V_sh[cur][kc][(ni * 16 + lm) * 32 + lgx];
        o[ni] = __builtin_amdgcn_mfma_f32_16x16x32_f16(pa, vb, o[ni], 0, 0, 0);
      }
    }
  }
#undef STAGE

  const int b = bh >> 4, h = bh & 15;
#pragma unroll
  for (int r = 0; r < 4; ++r) {
    float l = lsum[r];
    l += __shfl_xor(l, 1);
    l += __shfl_xor(l, 2);
    l += __shfl_xor(l, 4);
    l += __shfl_xor(l, 8);
    const float inv = 1.0f / l;
    const int nq = q0 + wave * 16 + lg * 4 + r;
    unsigned short* p = Ob + ((size_t)(b * 2048 + nq) * 16 + h) * 64 + lm;
    p[0] = f2h(o[0][r] * inv);
    p[16] = f2h(o[1][r] * inv);
    p[32] = f2h(o[2][r] * inv);
    p[48] = f2h(o[3][r] * inv);
  }
}

// ---------------------------------------------------------------------------
// Kernel 3: output projection, BK=32, 64x128 tile, fp16 MFMA.
// (round-10 version: dbuf async staging + XOR swizzle)
// ---------------------------------------------------------------------------
__global__ __launch_bounds__(256) void proj_gemm(
    const unsigned short* __restrict__ A, const unsigned short* __restrict__ Wb,
    const float* __restrict__ bias, float* __restrict__ Out) {
  __shared__ __align__(16) unsigned short A_sh[2][64 * 32];
  __shared__ __align__(16) unsigned short B_sh[2][128 * 32];
  const int n0 = blockIdx.x * 128, m0 = blockIdx.y * 64;
  const int tid = threadIdx.x, lane = tid & 63, wave = tid >> 6;
  const int wr = wave >> 1, wc = wave & 1, lm = lane & 15, lg = lane >> 4;
  const int r4 = lane >> 2;
  const int sg8 = (((lane & 3) ^ ((r4 >> 1) & 3)) * 8);
  const int lgx = (lg ^ ((lm >> 1) & 3)) * 8;

  f32x4 acc[2][4] = {};

#define PSTAGE(k0_, b_)                                                       \
  do {                                                                        \
    {                                                                         \
      const int row = wave * 16 + r4;                                         \
      GLOAD_LDS16(A + (size_t)(m0 + row) * 1024 + (k0_) + sg8,                \
                  &A_sh[b_][wave * 512]);                                     \
    }                                                                         \
    _Pragma("unroll")                                                         \
    for (int j = 0; j < 2; ++j) {                                             \
      const int chunk = wave * 2 + j;                                         \
      const int row = chunk * 16 + r4;                                        \
      GLOAD_LDS16(Wb + (size_t)(n0 + row) * 1024 + (k0_) + sg8,               \
                  &B_sh[b_][chunk * 512]);                                    \
    }                                                                         \
  } while (0)

  PSTAGE(0, 0);

  for (int it = 0; it < 32; ++it) {
    const int cur = it & 1;
    __syncthreads();
    if (it < 31) PSTAGE((it + 1) * 32, cur ^ 1);

    f16x8 af[2], bfr[4];
#pragma unroll
    for (int mi = 0; mi < 2; ++mi)
      af[mi] = *(const f16x8*)&A_sh[cur][(wr * 32 + mi * 16 + lm) * 32 + lgx];
#pragma unroll
    for (int ni = 0; ni < 4; ++ni)
      bfr[ni] = *(const f16x8*)&B_sh[cur][(wc * 64 + ni * 16 + lm) * 32 + lgx];
#pragma unroll
    for (int mi = 0; mi < 2; ++mi)
#pragma unroll
      for (int ni = 0; ni < 4; ++ni)
        acc[mi][ni] = __builtin_amdgcn_mfma_f32_16x16x32_f16(
            af[mi], bfr[ni], acc[mi][ni], 0, 0, 0);
  }
#undef PSTAGE

#pragma unroll
  for (int mi = 0; mi < 2; ++mi)
#pragma unroll
    for (int ni = 0; ni < 4; ++ni) {
      const int gn = n0 + wc * 64 + ni * 16 + lm;
      const float bv = bias[gn];
#pragma unroll
      for (int r = 0; r < 4; ++r) {
        const int gm = m0 + wr * 32 + mi * 16 + lg * 4 + r;
        Out[(size_t)gm * 1024 + gn] = acc[mi][ni][r] + bv;
      }
    }
}

extern "C" void kernel_launch(void* const* d_in, const int* in_sizes, int n_in,
                              void* d_out, int out_size, void* d_ws, size_t ws_size,
                              hipStream_t stream) {
  const float* x      = (const float*)d_in[0];
  const float* W_qkv  = (const float*)d_in[1];
  const float* b_qkv  = (const float*)d_in[2];
  const float* W_proj = (const float*)d_in[3];
  const float* b_proj = (const float*)d_in[4];
  float* out = (float*)d_out;

  unsigned short* Qb  = (unsigned short*)d_ws;
  unsigned short* Kb  = Qb + 4194304;
  unsigned short* Vt  = Kb + 4194304;
  unsigned short* Ao  = Vt + 4194304;
  unsigned short* Xb  = Ao + 4194304;
  unsigned short* Wqb = Xb + 4194304;
  unsigned short* Wpb = Wqb + 3145728;

  cvt_all<<<8192, 256, 0, stream>>>(x, W_qkv, W_proj, Xb, Wqb, Wpb);
  qkv_gemm<<<dim3(24, 32), 256, 0, stream>>>(Xb, Wqb, b_qkv, Qb, Kb, Vt);
  attn_kernel<<<dim3(16, 32), 512, 0, stream>>>(Qb, Kb, Vt, Ao);
  proj_gemm<<<dim3(8, 64), 256, 0, stream>>>(Ao, Wpb, b_proj, out);
}

// Round 3
// 193.043 us; speedup vs baseline: 1.0363x; 1.0070x over previous
//
#include <hip/hip_runtime.h>

typedef _Float16 f16x8 __attribute__((ext_vector_type(8)));
typedef __attribute__((ext_vector_type(4))) float f32x4;

// fp32 -> fp16 (RNE) bit pattern
static __device__ __forceinline__ unsigned short f2h(float f) {
  return __builtin_bit_cast(unsigned short, (_Float16)f);
}

// pack two fp32 -> one dword of two fp16 (RNE, matches old per-element path)
static __device__ __forceinline__ unsigned int pk2(float a, float b) {
  return (unsigned int)f2h(a) | ((unsigned int)f2h(b) << 16);
}

// raw v_exp_f32 (inputs bounded; fp16 margin absorbs the ~1ulp gap vs libm)
#if __has_builtin(__builtin_amdgcn_exp2f)
#define EXP2(x) __builtin_amdgcn_exp2f(x)
#else
#define EXP2(x) exp2f(x)
#endif

// async global->LDS, 16 B per lane; LDS dst = wave-uniform base + lane*16.
#define GLOAD_LDS16(gp, lp)                                          \
  __builtin_amdgcn_global_load_lds(                                  \
      (const __attribute__((address_space(1))) unsigned int*)(gp),   \
      (__attribute__((address_space(3))) unsigned int*)(lp), 16, 0, 0)

// ---------------------------------------------------------------------------
// Kernel 0: fp32 -> fp16 conversion for X, W_qkv, W_proj (one launch).
// ---------------------------------------------------------------------------
__global__ __launch_bounds__(256) void cvt_all(
    const float* __restrict__ X, const float* __restrict__ Wq,
    const float* __restrict__ Wp, unsigned short* __restrict__ Xb,
    unsigned short* __restrict__ Wqb, unsigned short* __restrict__ Wpb) {
  const int i = blockIdx.x * 256 + threadIdx.x;
  const float4* src;
  unsigned short* dst;
  int off;
  if (i < 1048576) {
    src = (const float4*)X; dst = Xb; off = i;
  } else if (i < 1835008) {
    src = (const float4*)Wq; dst = Wqb; off = i - 1048576;
  } else {
    src = (const float4*)Wp; dst = Wpb; off = i - 1835008;
  }
  const float4 v = src[off];
  *(ushort4*)(dst + (size_t)off * 4) =
      make_ushort4(f2h(v.x), f2h(v.y), f2h(v.z), f2h(v.w));
}

// ---------------------------------------------------------------------------
// Kernel 1: QKV projection.  256 threads / 4 waves (2x2 wave grid), each wave
// owns a 64x64 sub-tile (acc[4][4]) of the 128x128 tile.  8 ds_read_b128 feed
// 16 MFMA.  BK=32, glds dbuf (1 barrier/iter) + XOR column-group swizzle.
// Q pre-scaled by log2(e)/8.
//   Q,K: [B,H,2048,64] fp16     V: transposed [B,H,64,2048] fp16
// ---------------------------------------------------------------------------
__global__ __launch_bounds__(256, 3) void qkv_gemm(
    const unsigned short* __restrict__ Xb, const unsigned short* __restrict__ Wb,
    const float* __restrict__ bias, unsigned short* __restrict__ Qb,
    unsigned short* __restrict__ Kb, unsigned short* __restrict__ Vt) {
  __shared__ __align__(16) unsigned short A_sh[2][128 * 32];
  __shared__ __align__(16) unsigned short B_sh[2][128 * 32];
  const int n0 = blockIdx.x * 128, m0 = blockIdx.y * 128;
  const int tid = threadIdx.x, lane = tid & 63, wave = tid >> 6;  // 0..3
  const int wr = wave >> 1, wc = wave & 1;   // 2x2 wave grid, 64x64 each
  const int lm = lane & 15, lg = lane >> 4;
  const int r4 = lane >> 2;                              // staging row in chunk
  const int sg8 = (((lane & 3) ^ ((r4 >> 1) & 3)) * 8);  // swizzled src colgrp
  const int lgx = (lg ^ ((lm >> 1) & 3)) * 8;            // swizzled read colgrp

  f32x4 acc[4][4] = {};

#define QSTAGE(k0_, b_)                                                       \
  do {                                                                        \
    _Pragma("unroll")                                                         \
    for (int j = 0; j < 2; ++j) {                                             \
      const int chunk = wave * 2 + j;                                         \
      const int row = chunk * 16 + r4;                                        \
      GLOAD_LDS16(Xb + (size_t)(m0 + row) * 1024 + (k0_) + sg8,               \
                  &A_sh[b_][chunk * 512]);                                    \
      GLOAD_LDS16(Wb + (size_t)(n0 + row) * 1024 + (k0_) + sg8,               \
                  &B_sh[b_][chunk * 512]);                                    \
    }                                                                         \
  } while (0)

  QSTAGE(0, 0);

  for (int it = 0; it < 32; ++it) {
    const int cur = it & 1;
    __syncthreads();  // buf[cur] ready; buf[cur^1] free
    if (it < 31) QSTAGE((it + 1) * 32, cur ^ 1);  // fly during compute

    f16x8 af[4], bfr[4];
#pragma unroll
    for (int mi = 0; mi < 4; ++mi)
      af[mi] = *(const f16x8*)&A_sh[cur][(wr * 64 + mi * 16 + lm) * 32 + lgx];
#pragma unroll
    for (int ni = 0; ni < 4; ++ni)
      bfr[ni] = *(const f16x8*)&B_sh[cur][(wc * 64 + ni * 16 + lm) * 32 + lgx];
    __builtin_amdgcn_s_setprio(1);
#pragma unroll
    for (int mi = 0; mi < 4; ++mi)
#pragma unroll
      for (int ni = 0; ni < 4; ++ni)
        acc[mi][ni] = __builtin_amdgcn_mfma_f32_16x16x32_f16(
            af[mi], bfr[ni], acc[mi][ni], 0, 0, 0);
    __builtin_amdgcn_s_setprio(0);
  }
#undef QSTAGE

  const float qscale = 0.18033688011112042f;  // log2(e)/8  (folded attn scale)
#pragma unroll
  for (int mi = 0; mi < 4; ++mi) {
#pragma unroll
    for (int ni = 0; ni < 4; ++ni) {
      const int gn = n0 + wc * 64 + ni * 16 + lm;
      const float bv = bias[gn];
      const int which = gn >> 10;
      const int h = (gn >> 6) & 15;
      const int hd = gn & 63;
      float v[4];
#pragma unroll
      for (int r = 0; r < 4; ++r) v[r] = acc[mi][ni][r] + bv;
      const int gm0 = m0 + wr * 64 + mi * 16 + lg * 4;
      const int bb = gm0 >> 11;
      const int nq0 = gm0 & 2047;
      if (which == 0) {
        unsigned short* p = Qb + (((size_t)bb * 16 + h) * 2048 + nq0) * 64 + hd;
        p[0] = f2h(v[0] * qscale);   p[64] = f2h(v[1] * qscale);
        p[128] = f2h(v[2] * qscale); p[192] = f2h(v[3] * qscale);
      } else if (which == 1) {
        unsigned short* p = Kb + (((size_t)bb * 16 + h) * 2048 + nq0) * 64 + hd;
        p[0] = f2h(v[0]);   p[64] = f2h(v[1]);
        p[128] = f2h(v[2]); p[192] = f2h(v[3]);
      } else {
        *(ushort4*)(Vt + (((size_t)bb * 16 + h) * 64 + hd) * 2048 + nq0) =
            make_ushort4(f2h(v[0]), f2h(v[1]), f2h(v[2]), f2h(v[3]));
      }
    }
  }
}

// ---------------------------------------------------------------------------
// Kernel 2: flash attention.  NEW this round: P_sh ELIMINATED via swapped
// QK^T (s = mfma(kf, qf) -> lane holds P[q=lm][k=ni*16+lg*4+r]) + in-register
// repack to the PV A-fragment with permlane32_swap/permlane16_swap pairs
// (verified algebra: pa[kc].d{0,2} = pl16(pl32(W[2kc][0], W[2kc+1][0])),
// d{1,3} from w=1).  LDS ops per wave-iter: 34 -> 16 (was the measured
// bottleneck: 16 waves x 312cyc/iter = wall clock).  Q/K/V loads, O layout,
// staging, swizzle identical to the 62.5us version.
// ---------------------------------------------------------------------------
__global__ __launch_bounds__(512, 4) void attn_kernel(
    const unsigned short* __restrict__ Qb, const unsigned short* __restrict__ Kb,
    const unsigned short* __restrict__ Vt, unsigned short* __restrict__ Ob) {
  __shared__ __align__(16) unsigned short K_sh[2][2][64 * 32];
  __shared__ __align__(16) unsigned short V_sh[2][2][64 * 32];
  const int bh = blockIdx.y, q0 = blockIdx.x * 128;
  const size_t base = (size_t)bh * (2048 * 64);
  const unsigned short* Qp = Qb + base;
  const unsigned short* Kp = Kb + base;
  const unsigned short* Vp = Vt + base;  // [64][2048]
  const int tid = threadIdx.x, lane = tid & 63, wave = tid >> 6;  // 0..7
  const int lm = lane & 15, lg = lane >> 4;
  const int r4 = lane >> 2;
  const int sg8 = (((lane & 3) ^ ((r4 >> 1) & 3)) * 8);
  const int lgx = (lg ^ ((lm >> 1) & 3)) * 8;

  f16x8 qf[2];
#pragma unroll
  for (int kc = 0; kc < 2; ++kc)
    qf[kc] = *(const f16x8*)(Qp +
        (size_t)(q0 + wave * 16 + lm) * 64 + kc * 32 + lg * 8);

  f32x4 o[4] = {};
  float lsum = 0.0f;

  const bool isV = wave >= 4;
  const int plane = wave & 1;
  const int half = (wave >> 1) & 1;

#define STAGE(kt_, b_)                                                        \
  do {                                                                        \
    if (!isV) {                                                               \
      _Pragma("unroll")                                                       \
      for (int qv = 0; qv < 2; ++qv)                                          \
        GLOAD_LDS16(Kp + (size_t)((kt_) * 64 + half * 32 + qv * 16 + r4) * 64 \
                        + plane * 32 + sg8,                                   \
                    &K_sh[b_][plane][(half * 2 + qv) * 512]);                 \
    } else {                                                                  \
      _Pragma("unroll")                                                       \
      for (int qv = 0; qv < 2; ++qv)                                          \
        GLOAD_LDS16(Vp + (size_t)(half * 32 + qv * 16 + r4) * 2048 +          \
                        (kt_) * 64 + plane * 32 + sg8,                        \
                    &V_sh[b_][plane][(half * 2 + qv) * 512]);                 \
    }                                                                         \
  } while (0)

  STAGE(0, 0);

  for (int kt = 0; kt < 32; ++kt) {
    const int cur = kt & 1;
    __syncthreads();
    if (kt < 31) STAGE(kt + 1, cur ^ 1);

    // ---- swapped QK^T: lane holds P[q = q0+wave*16+lm][k = ni*16+lg*4+r]
    f32x4 s[4] = {};
#pragma unroll
    for (int kc = 0; kc < 2; ++kc) {
#pragma unroll
      for (int ni = 0; ni < 4; ++ni) {
        const f16x8 kf =
            *(const f16x8*)&K_sh[cur][kc][(ni * 16 + lm) * 32 + lgx];
        s[ni] = __builtin_amdgcn_mfma_f32_16x16x32_f16(kf, qf[kc], s[ni], 0, 0, 0);
      }
    }

    // ---- exp2 + pack: W[ni][w] = f16x2(p[2w], p[2w+1]) ----
    unsigned int Wp_[4][2];
#pragma unroll
    for (int ni = 0; ni < 4; ++ni) {
      const float p0 = EXP2(s[ni][0]), p1 = EXP2(s[ni][1]);
      const float p2 = EXP2(s[ni][2]), p3 = EXP2(s[ni][3]);
      lsum += (p0 + p1) + (p2 + p3);
      Wp_[ni][0] = pk2(p0, p1);
      Wp_[ni][1] = pk2(p2, p3);
    }

    // ---- in-register P -> PV A-fragment via permlane swaps ----
#pragma unroll
    for (int kc = 0; kc < 2; ++kc) {
      auto t0 = __builtin_amdgcn_permlane32_swap(Wp_[2 * kc][0], Wp_[2 * kc + 1][0],
                                                 false, false);
      auto u0 = __builtin_amdgcn_permlane16_swap(t0[0], t0[1], false, false);
      auto t1 = __builtin_amdgcn_permlane32_swap(Wp_[2 * kc][1], Wp_[2 * kc + 1][1],
                                                 false, false);
      auto u1 = __builtin_amdgcn_permlane16_swap(t1[0], t1[1], false, false);
      union { unsigned int u[4]; f16x8 v; } pa;
      pa.u[0] = u0[0];  // k = lg*8 + {0,1}
      pa.u[1] = u1[0];  // k = lg*8 + {2,3}
      pa.u[2] = u0[1];  // k = lg*8 + {4,5}
      pa.u[3] = u1[1];  // k = lg*8 + {6,7}
#pragma unroll
      for (int ni = 0; ni < 4; ++ni) {
        const f16x8 vb =
            *(const f16x8*)&V_sh[cur][kc][(ni * 16 + lm) * 32 + lgx];
        o[ni] = __builtin_amdgcn_mfma_f32_16x16x32_f16(pa.v, vb, o[ni], 0, 0, 0);
      }
    }
  }
#undef STAGE

  // lsum: lane holds partial for q = q0+wave*16+lm over keys {ni*16+lg*4+r};
  // total across lg-groups, then fetch the sum for q = lg*4+r (O layout).
  float total = lsum;
  total += __shfl_xor(total, 16);
  total += __shfl_xor(total, 32);

  const int b = bh >> 4, h = bh & 15;
#pragma unroll
  for (int r = 0; r < 4; ++r) {
    const float inv = 1.0f / __shfl(total, (lane & 48) | (lg * 4 + r));
    const int nq = q0 + wave * 16 + lg * 4 + r;
    unsigned short* p = Ob + ((size_t)(b * 2048 + nq) * 16 + h) * 64 + lm;
    p[0] = f2h(o[0][r] * inv);
    p[16] = f2h(o[1][r] * inv);
    p[32] = f2h(o[2][r] * inv);
    p[48] = f2h(o[3][r] * inv);
  }
}

// ---------------------------------------------------------------------------
// Kernel 3: output projection, BK=32, 64x128 tile, fp16 MFMA.
// (round-10 version: dbuf async staging + XOR swizzle)
// ---------------------------------------------------------------------------
__global__ __launch_bounds__(256) void proj_gemm(
    const unsigned short* __restrict__ A, const unsigned short* __restrict__ Wb,
    const float* __restrict__ bias, float* __restrict__ Out) {
  __shared__ __align__(16) unsigned short A_sh[2][64 * 32];
  __shared__ __align__(16) unsigned short B_sh[2][128 * 32];
  const int n0 = blockIdx.x * 128, m0 = blockIdx.y * 64;
  const int tid = threadIdx.x, lane = tid & 63, wave = tid >> 6;
  const int wr = wave >> 1, wc = wave & 1, lm = lane & 15, lg = lane >> 4;
  const int r4 = lane >> 2;
  const int sg8 = (((lane & 3) ^ ((r4 >> 1) & 3)) * 8);
  const int lgx = (lg ^ ((lm >> 1) & 3)) * 8;

  f32x4 acc[2][4] = {};

#define PSTAGE(k0_, b_)                                                       \
  do {                                                                        \
    {                                                                         \
      const int row = wave * 16 + r4;                                         \
      GLOAD_LDS16(A + (size_t)(m0 + row) * 1024 + (k0_) + sg8,                \
                  &A_sh[b_][wave * 512]);                                     \
    }                                                                         \
    _Pragma("unroll")                                                         \
    for (int j = 0; j < 2; ++j) {                                             \
      const int chunk = wave * 2 + j;                                         \
      const int row = chunk * 16 + r4;                                        \
      GLOAD_LDS16(Wb + (size_t)(n0 + row) * 1024 + (k0_) + sg8,               \
                  &B_sh[b_][chunk * 512]);                                    \
    }                                                                         \
  } while (0)

  PSTAGE(0, 0);

  for (int it = 0; it < 32; ++it) {
    const int cur = it & 1;
    __syncthreads();
    if (it < 31) PSTAGE((it + 1) * 32, cur ^ 1);

    f16x8 af[2], bfr[4];
#pragma unroll
    for (int mi = 0; mi < 2; ++mi)
      af[mi] = *(const f16x8*)&A_sh[cur][(wr * 32 + mi * 16 + lm) * 32 + lgx];
#pragma unroll
    for (int ni = 0; ni < 4; ++ni)
      bfr[ni] = *(const f16x8*)&B_sh[cur][(wc * 64 + ni * 16 + lm) * 32 + lgx];
#pragma unroll
    for (int mi = 0; mi < 2; ++mi)
#pragma unroll
      for (int ni = 0; ni < 4; ++ni)
        acc[mi][ni] = __builtin_amdgcn_mfma_f32_16x16x32_f16(
            af[mi], bfr[ni], acc[mi][ni], 0, 0, 0);
  }
#undef PSTAGE

#pragma unroll
  for (int mi = 0; mi < 2; ++mi)
#pragma unroll
    for (int ni = 0; ni < 4; ++ni) {
      const int gn = n0 + wc * 64 + ni * 16 + lm;
      const float bv = bias[gn];
#pragma unroll
      for (int r = 0; r < 4; ++r) {
        const int gm = m0 + wr * 32 + mi * 16 + lg * 4 + r;
        Out[(size_t)gm * 1024 + gn] = acc[mi][ni][r] + bv;
      }
    }
}

extern "C" void kernel_launch(void* const* d_in, const int* in_sizes, int n_in,
                              void* d_out, int out_size, void* d_ws, size_t ws_size,
                              hipStream_t stream) {
  const float* x      = (const float*)d_in[0];
  const float* W_qkv  = (const float*)d_in[1];
  const float* b_qkv  = (const float*)d_in[2];
  const float* W_proj = (const float*)d_in[3];
  const float* b_proj = (const float*)d_in[4];
  float* out = (float*)d_out;

  unsigned short* Qb  = (unsigned short*)d_ws;
  unsigned short* Kb  = Qb + 4194304;
  unsigned short* Vt  = Kb + 4194304;
  unsigned short* Ao  = Vt + 4194304;
  unsigned short* Xb  = Ao + 4194304;
  unsigned short* Wqb = Xb + 4194304;
  unsigned short* Wpb = Wqb + 3145728;

  cvt_all<<<8192, 256, 0, stream>>>(x, W_qkv, W_proj, Xb, Wqb, Wpb);
  qkv_gemm<<<dim3(24, 32), 256, 0, stream>>>(Xb, Wqb, b_qkv, Qb, Kb, Vt);
  attn_kernel<<<dim3(16, 32), 512, 0, stream>>>(Qb, Kb, Vt, Ao);
  proj_gemm<<<dim3(8, 64), 256, 0, stream>>>(Ao, Wpb, b_proj, out);
}

// Round 6
// 186.194 us; speedup vs baseline: 1.0744x; 1.0368x over previous
//
#include <hip/hip_runtime.h>

typedef _Float16 f16x8 __attribute__((ext_vector_type(8)));
typedef __attribute__((ext_vector_type(4))) float f32x4;

// fp32 -> fp16 (RNE) bit pattern
static __device__ __forceinline__ unsigned short f2h(float f) {
  return __builtin_bit_cast(unsigned short, (_Float16)f);
}

// pack two fp32 -> one dword of two fp16 (RNE, matches old per-element path)
static __device__ __forceinline__ unsigned int pk2(float a, float b) {
  return (unsigned int)f2h(a) | ((unsigned int)f2h(b) << 16);
}

// raw v_exp_f32 (inputs bounded; fp16 margin absorbs the ~1ulp gap vs libm)
#if __has_builtin(__builtin_amdgcn_exp2f)
#define EXP2(x) __builtin_amdgcn_exp2f(x)
#else
#define EXP2(x) exp2f(x)
#endif

// async global->LDS, 16 B per lane; LDS dst = wave-uniform base + lane*16.
#define GLOAD_LDS16(gp, lp)                                          \
  __builtin_amdgcn_global_load_lds(                                  \
      (const __attribute__((address_space(1))) unsigned int*)(gp),   \
      (__attribute__((address_space(3))) unsigned int*)(lp), 16, 0, 0)

// ---------------------------------------------------------------------------
// Kernel 0: fp32 -> fp16 conversion for X, W_qkv, W_proj (one launch).
// ---------------------------------------------------------------------------
__global__ __launch_bounds__(256) void cvt_all(
    const float* __restrict__ X, const float* __restrict__ Wq,
    const float* __restrict__ Wp, unsigned short* __restrict__ Xb,
    unsigned short* __restrict__ Wqb, unsigned short* __restrict__ Wpb) {
  const int i = blockIdx.x * 256 + threadIdx.x;
  const float4* src;
  unsigned short* dst;
  int off;
  if (i < 1048576) {
    src = (const float4*)X; dst = Xb; off = i;
  } else if (i < 1835008) {
    src = (const float4*)Wq; dst = Wqb; off = i - 1048576;
  } else {
    src = (const float4*)Wp; dst = Wpb; off = i - 1835008;
  }
  const float4 v = src[off];
  *(ushort4*)(dst + (size_t)off * 4) =
      make_ushort4(f2h(v.x), f2h(v.y), f2h(v.z), f2h(v.w));
}

// ---------------------------------------------------------------------------
// Kernel 1: QKV projection.  256 threads / 4 waves (2x2 wave grid), each wave
// owns a 64x64 sub-tile (acc[4][4]) of the 128x128 tile.  8 ds_read_b128 feed
// 16 MFMA.  BK=32, glds dbuf (1 barrier/iter) + XOR column-group swizzle.
// Q pre-scaled by log2(e)/8.
//   Q,K: [B,H,2048,64] fp16     V: transposed [B,H,64,2048] fp16
// ---------------------------------------------------------------------------
__global__ __launch_bounds__(256, 3) void qkv_gemm(
    const unsigned short* __restrict__ Xb, const unsigned short* __restrict__ Wb,
    const float* __restrict__ bias, unsigned short* __restrict__ Qb,
    unsigned short* __restrict__ Kb, unsigned short* __restrict__ Vt) {
  __shared__ __align__(16) unsigned short A_sh[2][128 * 32];
  __shared__ __align__(16) unsigned short B_sh[2][128 * 32];
  const int n0 = blockIdx.x * 128, m0 = blockIdx.y * 128;
  const int tid = threadIdx.x, lane = tid & 63, wave = tid >> 6;  // 0..3
  const int wr = wave >> 1, wc = wave & 1;   // 2x2 wave grid, 64x64 each
  const int lm = lane & 15, lg = lane >> 4;
  const int r4 = lane >> 2;                              // staging row in chunk
  const int sg8 = (((lane & 3) ^ ((r4 >> 1) & 3)) * 8);  // swizzled src colgrp
  const int lgx = (lg ^ ((lm >> 1) & 3)) * 8;            // swizzled read colgrp

  f32x4 acc[4][4] = {};

#define QSTAGE(k0_, b_)                                                       \
  do {                                                                        \
    _Pragma("unroll")                                                         \
    for (int j = 0; j < 2; ++j) {                                             \
      const int chunk = wave * 2 + j;                                         \
      const int row = chunk * 16 + r4;                                        \
      GLOAD_LDS16(Xb + (size_t)(m0 + row) * 1024 + (k0_) + sg8,               \
                  &A_sh[b_][chunk * 512]);                                    \
      GLOAD_LDS16(Wb + (size_t)(n0 + row) * 1024 + (k0_) + sg8,               \
                  &B_sh[b_][chunk * 512]);                                    \
    }                                                                         \
  } while (0)

  QSTAGE(0, 0);

  for (int it = 0; it < 32; ++it) {
    const int cur = it & 1;
    __syncthreads();  // buf[cur] ready; buf[cur^1] free
    if (it < 31) QSTAGE((it + 1) * 32, cur ^ 1);  // fly during compute

    f16x8 af[4], bfr[4];
#pragma unroll
    for (int mi = 0; mi < 4; ++mi)
      af[mi] = *(const f16x8*)&A_sh[cur][(wr * 64 + mi * 16 + lm) * 32 + lgx];
#pragma unroll
    for (int ni = 0; ni < 4; ++ni)
      bfr[ni] = *(const f16x8*)&B_sh[cur][(wc * 64 + ni * 16 + lm) * 32 + lgx];
    __builtin_amdgcn_s_setprio(1);
#pragma unroll
    for (int mi = 0; mi < 4; ++mi)
#pragma unroll
      for (int ni = 0; ni < 4; ++ni)
        acc[mi][ni] = __builtin_amdgcn_mfma_f32_16x16x32_f16(
            af[mi], bfr[ni], acc[mi][ni], 0, 0, 0);
    __builtin_amdgcn_s_setprio(0);
  }
#undef QSTAGE

  const float qscale = 0.18033688011112042f;  // log2(e)/8  (folded attn scale)
#pragma unroll
  for (int mi = 0; mi < 4; ++mi) {
#pragma unroll
    for (int ni = 0; ni < 4; ++ni) {
      const int gn = n0 + wc * 64 + ni * 16 + lm;
      const float bv = bias[gn];
      const int which = gn >> 10;
      const int h = (gn >> 6) & 15;
      const int hd = gn & 63;
      float v[4];
#pragma unroll
      for (int r = 0; r < 4; ++r) v[r] = acc[mi][ni][r] + bv;
      const int gm0 = m0 + wr * 64 + mi * 16 + lg * 4;
      const int bb = gm0 >> 11;
      const int nq0 = gm0 & 2047;
      if (which == 0) {
        unsigned short* p = Qb + (((size_t)bb * 16 + h) * 2048 + nq0) * 64 + hd;
        p[0] = f2h(v[0] * qscale);   p[64] = f2h(v[1] * qscale);
        p[128] = f2h(v[2] * qscale); p[192] = f2h(v[3] * qscale);
      } else if (which == 1) {
        unsigned short* p = Kb + (((size_t)bb * 16 + h) * 2048 + nq0) * 64 + hd;
        p[0] = f2h(v[0]);   p[64] = f2h(v[1]);
        p[128] = f2h(v[2]); p[192] = f2h(v[3]);
      } else {
        *(ushort4*)(Vt + (((size_t)bb * 16 + h) * 64 + hd) * 2048 + nq0) =
            make_ushort4(f2h(v[0]), f2h(v[1]), f2h(v[2]), f2h(v[3]));
      }
    }
  }
}

// ---------------------------------------------------------------------------
// Kernel 2: flash attention.  KV-SPLIT across wave pairs (round-5 theory),
// with the merge in a DEDICATED LDS region (round-5's aliased-merge was the
// prime suspect for its nondeterministic refcheck failure).
// 8 waves = 4 q-groups x 2 kv-halves; each wave computes 32 q-rows x 32 kv
// per tile.  LDS fragment reads per wave-iter: 16 -> 8 (measured top pipe:
// 3072/4470 cyc/CU-iter).  Swapped QK^T + permlane P-repack retained
// (refcheck-verified round 3; re-derived from ISA semantics).
// Staging arrays byte-identical to the verified round-3 kernel.
// ---------------------------------------------------------------------------
__global__ __launch_bounds__(512, 4) void attn_kernel(
    const unsigned short* __restrict__ Qb, const unsigned short* __restrict__ Kb,
    const unsigned short* __restrict__ Vt, unsigned short* __restrict__ Ob) {
  __shared__ __align__(16) unsigned short K_sh[2][2][64 * 32];
  __shared__ __align__(16) unsigned short V_sh[2][2][64 * 32];
  __shared__ __align__(16) f32x4 Om[4][4][64];   // 16 KB merge buffer
  __shared__ float Ls2[4][64];                   // 1 KB lsum merge
  const int bh = blockIdx.y, q0 = blockIdx.x * 128;
  const size_t base = (size_t)bh * (2048 * 64);
  const unsigned short* Qp = Qb + base;
  const unsigned short* Kp = Kb + base;
  const unsigned short* Vp = Vt + base;  // [64][2048]
  const int tid = threadIdx.x, lane = tid & 63, wave = tid >> 6;  // 0..7
  const int lm = lane & 15, lg = lane >> 4;
  const int r4 = lane >> 2;
  const int sg8 = (((lane & 3) ^ ((r4 >> 1) & 3)) * 8);
  const int lgx = (lg ^ ((lm >> 1) & 3)) * 8;

  const int qg = wave >> 1;      // 0..3 : q-group (32 rows)
  const int khalf = wave & 1;    // 0/1  : kv half within each 64-tile

  f16x8 qf[2][2];
#pragma unroll
  for (int mi = 0; mi < 2; ++mi)
#pragma unroll
    for (int kc = 0; kc < 2; ++kc)
      qf[mi][kc] = *(const f16x8*)(Qp +
          (size_t)(q0 + qg * 32 + mi * 16 + lm) * 64 + kc * 32 + lg * 8);

  f32x4 o[2][4] = {};
  float lsum[2] = {0.0f, 0.0f};

  const bool isV = wave >= 4;
  const int plane = wave & 1;
  const int half = (wave >> 1) & 1;

#define STAGE(kt_, b_)                                                        \
  do {                                                                        \
    if (!isV) {                                                               \
      _Pragma("unroll")                                                       \
      for (int qv = 0; qv < 2; ++qv)                                          \
        GLOAD_LDS16(Kp + (size_t)((kt_) * 64 + half * 32 + qv * 16 + r4) * 64 \
                        + plane * 32 + sg8,                                   \
                    &K_sh[b_][plane][(half * 2 + qv) * 512]);                 \
    } else {                                                                  \
      _Pragma("unroll")                                                       \
      for (int qv = 0; qv < 2; ++qv)                                          \
        GLOAD_LDS16(Vp + (size_t)(half * 32 + qv * 16 + r4) * 2048 +          \
                        (kt_) * 64 + plane * 32 + sg8,                        \
                    &V_sh[b_][plane][(half * 2 + qv) * 512]);                 \
    }                                                                         \
  } while (0)

  STAGE(0, 0);

  for (int kt = 0; kt < 32; ++kt) {
    const int cur = kt & 1;
    __syncthreads();
    if (kt < 31) STAGE(kt + 1, cur ^ 1);

    // ---- swapped QK^T on this wave's kv half:
    // lane holds P[q = q0+qg*32+mi*16+lm][k = khalf*32 + ni*16 + lg*4 + r]
    f32x4 s[2][2] = {};
#pragma unroll
    for (int kc = 0; kc < 2; ++kc) {
#pragma unroll
      for (int ni = 0; ni < 2; ++ni) {
        const f16x8 kf = *(const f16x8*)
            &K_sh[cur][kc][(khalf * 32 + ni * 16 + lm) * 32 + lgx];
        s[0][ni] = __builtin_amdgcn_mfma_f32_16x16x32_f16(
            kf, qf[0][kc], s[0][ni], 0, 0, 0);
        s[1][ni] = __builtin_amdgcn_mfma_f32_16x16x32_f16(
            kf, qf[1][kc], s[1][ni], 0, 0, 0);
      }
    }

    // ---- exp2 + pack: Wp_[mi][ni][w] = f16x2(p[2w], p[2w+1]) ----
    unsigned int Wp_[2][2][2];
#pragma unroll
    for (int mi = 0; mi < 2; ++mi)
#pragma unroll
      for (int ni = 0; ni < 2; ++ni) {
        const float p0 = EXP2(s[mi][ni][0]), p1 = EXP2(s[mi][ni][1]);
        const float p2 = EXP2(s[mi][ni][2]), p3 = EXP2(s[mi][ni][3]);
        lsum[mi] += (p0 + p1) + (p2 + p3);
        Wp_[mi][ni][0] = pk2(p0, p1);
        Wp_[mi][ni][1] = pk2(p2, p3);
      }

    // ---- V fragments for this wave's kv half (4 reads, reused by both mi)
    f16x8 vb[4];
#pragma unroll
    for (int ni = 0; ni < 4; ++ni)
      vb[ni] = *(const f16x8*)&V_sh[cur][khalf][(ni * 16 + lm) * 32 + lgx];

    // ---- in-register P -> PV A-fragment via permlane swaps (K=32) ----
#pragma unroll
    for (int mi = 0; mi < 2; ++mi) {
      auto t0 = __builtin_amdgcn_permlane32_swap(Wp_[mi][0][0], Wp_[mi][1][0],
                                                 false, false);
      auto u0 = __builtin_amdgcn_permlane16_swap(t0[0], t0[1], false, false);
      auto t1 = __builtin_amdgcn_permlane32_swap(Wp_[mi][0][1], Wp_[mi][1][1],
                                                 false, false);
      auto u1 = __builtin_amdgcn_permlane16_swap(t1[0], t1[1], false, false);
      union { unsigned int u[4]; f16x8 v; } pa;
      pa.u[0] = u0[0];  // k = lg*8 + {0,1}
      pa.u[1] = u1[0];  // k = lg*8 + {2,3}
      pa.u[2] = u0[1];  // k = lg*8 + {4,5}
      pa.u[3] = u1[1];  // k = lg*8 + {6,7}
#pragma unroll
      for (int ni = 0; ni < 4; ++ni)
        o[mi][ni] = __builtin_amdgcn_mfma_f32_16x16x32_f16(
            pa.v, vb[ni], o[mi][ni], 0, 0, 0);
    }
  }
#undef STAGE

  // ---- merge the two kv-halves via dedicated LDS, one mi-pass at a time ----
  const int b = bh >> 4, h = bh & 15;
#pragma unroll
  for (int mi = 0; mi < 2; ++mi) {
    __syncthreads();
    if (khalf == 1) {
#pragma unroll
      for (int ni = 0; ni < 4; ++ni) Om[qg][ni][lane] = o[mi][ni];
      Ls2[qg][lane] = lsum[mi];
    }
    __syncthreads();
    if (khalf == 0) {
#pragma unroll
      for (int ni = 0; ni < 4; ++ni) {
        const f32x4 t = Om[qg][ni][lane];
        o[mi][ni][0] += t[0]; o[mi][ni][1] += t[1];
        o[mi][ni][2] += t[2]; o[mi][ni][3] += t[3];
      }
      float total = lsum[mi] + Ls2[qg][lane];
      total += __shfl_xor(total, 16);
      total += __shfl_xor(total, 32);
#pragma unroll
      for (int r = 0; r < 4; ++r) {
        const float inv = 1.0f / __shfl(total, (lane & 48) | (lg * 4 + r));
        const int nq = q0 + qg * 32 + mi * 16 + lg * 4 + r;
        unsigned short* p = Ob + ((size_t)(b * 2048 + nq) * 16 + h) * 64 + lm;
        p[0] = f2h(o[mi][0][r] * inv);
        p[16] = f2h(o[mi][1][r] * inv);
        p[32] = f2h(o[mi][2][r] * inv);
        p[48] = f2h(o[mi][3][r] * inv);
      }
    }
  }
}

// ---------------------------------------------------------------------------
// Kernel 3: output projection, BK=32, 64x128 tile, fp16 MFMA.
// (round-10 version: dbuf async staging + XOR swizzle)
// ---------------------------------------------------------------------------
__global__ __launch_bounds__(256) void proj_gemm(
    const unsigned short* __restrict__ A, const unsigned short* __restrict__ Wb,
    const float* __restrict__ bias, float* __restrict__ Out) {
  __shared__ __align__(16) unsigned short A_sh[2][64 * 32];
  __shared__ __align__(16) unsigned short B_sh[2][128 * 32];
  const int n0 = blockIdx.x * 128, m0 = blockIdx.y * 64;
  const int tid = threadIdx.x, lane = tid & 63, wave = tid >> 6;
  const int wr = wave >> 1, wc = wave & 1, lm = lane & 15, lg = lane >> 4;
  const int r4 = lane >> 2;
  const int sg8 = (((lane & 3) ^ ((r4 >> 1) & 3)) * 8);
  const int lgx = (lg ^ ((lm >> 1) & 3)) * 8;

  f32x4 acc[2][4] = {};

#define PSTAGE(k0_, b_)                                                       \
  do {                                                                        \
    {                                                                         \
      const int row = wave * 16 + r4;                                         \
      GLOAD_LDS16(A + (size_t)(m0 + row) * 1024 + (k0_) + sg8,                \
                  &A_sh[b_][wave * 512]);                                     \
    }                                                                         \
    _Pragma("unroll")                                                         \
    for (int j = 0; j < 2; ++j) {                                             \
      const int chunk = wave * 2 + j;                                         \
      const int row = chunk * 16 + r4;                                        \
      GLOAD_LDS16(Wb + (size_t)(n0 + row) * 1024 + (k0_) + sg8,               \
                  &B_sh[b_][chunk * 512]);                                    \
    }                                                                         \
  } while (0)

  PSTAGE(0, 0);

  for (int it = 0; it < 32; ++it) {
    const int cur = it & 1;
    __syncthreads();
    if (it < 31) PSTAGE((it + 1) * 32, cur ^ 1);

    f16x8 af[2], bfr[4];
#pragma unroll
    for (int mi = 0; mi < 2; ++mi)
      af[mi] = *(const f16x8*)&A_sh[cur][(wr * 32 + mi * 16 + lm) * 32 + lgx];
#pragma unroll
    for (int ni = 0; ni < 4; ++ni)
      bfr[ni] = *(const f16x8*)&B_sh[cur][(wc * 64 + ni * 16 + lm) * 32 + lgx];
#pragma unroll
    for (int mi = 0; mi < 2; ++mi)
#pragma unroll
      for (int ni = 0; ni < 4; ++ni)
        acc[mi][ni] = __builtin_amdgcn_mfma_f32_16x16x32_f16(
            af[mi], bfr[ni], acc[mi][ni], 0, 0, 0);
  }
#undef PSTAGE

#pragma unroll
  for (int mi = 0; mi < 2; ++mi)
#pragma unroll
    for (int ni = 0; ni < 4; ++ni) {
      const int gn = n0 + wc * 64 + ni * 16 + lm;
      const float bv = bias[gn];
#pragma unroll
      for (int r = 0; r < 4; ++r) {
        const int gm = m0 + wr * 32 + mi * 16 + lg * 4 + r;
        Out[(size_t)gm * 1024 + gn] = acc[mi][ni][r] + bv;
      }
    }
}

extern "C" void kernel_launch(void* const* d_in, const int* in_sizes, int n_in,
                              void* d_out, int out_size, void* d_ws, size_t ws_size,
                              hipStream_t stream) {
  const float* x      = (const float*)d_in[0];
  const float* W_qkv  = (const float*)d_in[1];
  const float* b_qkv  = (const float*)d_in[2];
  const float* W_proj = (const float*)d_in[3];
  const float* b_proj = (const float*)d_in[4];
  float* out = (float*)d_out;

  unsigned short* Qb  = (unsigned short*)d_ws;
  unsigned short* Kb  = Qb + 4194304;
  unsigned short* Vt  = Kb + 4194304;
  unsigned short* Ao  = Vt + 4194304;
  unsigned short* Xb  = Ao + 4194304;
  unsigned short* Wqb = Xb + 4194304;
  unsigned short* Wpb = Wqb + 3145728;

  cvt_all<<<8192, 256, 0, stream>>>(x, W_qkv, W_proj, Xb, Wqb, Wpb);
  qkv_gemm<<<dim3(24, 32), 256, 0, stream>>>(Xb, Wqb, b_qkv, Qb, Kb, Vt);
  attn_kernel<<<dim3(16, 32), 512, 0, stream>>>(Qb, Kb, Vt, Ao);
  proj_gemm<<<dim3(8, 64), 256, 0, stream>>>(Ao, Wpb, b_proj, out);
}

// Round 7
// 183.983 us; speedup vs baseline: 1.0873x; 1.0120x over previous
//
#include <hip/hip_runtime.h>

typedef _Float16 f16x8 __attribute__((ext_vector_type(8)));
typedef __attribute__((ext_vector_type(4))) float f32x4;

// fp32 -> fp16 (RNE) bit pattern
static __device__ __forceinline__ unsigned short f2h(float f) {
  return __builtin_bit_cast(unsigned short, (_Float16)f);
}

// pack two fp32 -> one dword of two fp16
static __device__ __forceinline__ unsigned int pk2(float a, float b) {
  return (unsigned int)f2h(a) | ((unsigned int)f2h(b) << 16);
}

// packed RTZ convert (1 VALU op vs 3); numerator/denominator bias cancels
#if __has_builtin(__builtin_amdgcn_cvt_pkrtz)
static __device__ __forceinline__ unsigned int pkrtz(float a, float b) {
  return __builtin_bit_cast(unsigned int, __builtin_amdgcn_cvt_pkrtz(a, b));
}
#else
#define pkrtz pk2
#endif

// raw v_exp_f32 (inputs bounded; fp16 margin absorbs the ~1ulp gap vs libm)
#if __has_builtin(__builtin_amdgcn_exp2f)
#define EXP2(x) __builtin_amdgcn_exp2f(x)
#else
#define EXP2(x) exp2f(x)
#endif

// async global->LDS, 16 B per lane; LDS dst = wave-uniform base + lane*16.
#define GLOAD_LDS16(gp, lp)                                          \
  __builtin_amdgcn_global_load_lds(                                  \
      (const __attribute__((address_space(1))) unsigned int*)(gp),   \
      (__attribute__((address_space(3))) unsigned int*)(lp), 16, 0, 0)

// ---------------------------------------------------------------------------
// Kernel 0: fp32 -> fp16 conversion for X, W_qkv, W_proj (one launch).
// ---------------------------------------------------------------------------
__global__ __launch_bounds__(256) void cvt_all(
    const float* __restrict__ X, const float* __restrict__ Wq,
    const float* __restrict__ Wp, unsigned short* __restrict__ Xb,
    unsigned short* __restrict__ Wqb, unsigned short* __restrict__ Wpb) {
  const int i = blockIdx.x * 256 + threadIdx.x;
  const float4* src;
  unsigned short* dst;
  int off;
  if (i < 1048576) {
    src = (const float4*)X; dst = Xb; off = i;
  } else if (i < 1835008) {
    src = (const float4*)Wq; dst = Wqb; off = i - 1048576;
  } else {
    src = (const float4*)Wp; dst = Wpb; off = i - 1835008;
  }
  const float4 v = src[off];
  *(ushort4*)(dst + (size_t)off * 4) =
      make_ushort4(f2h(v.x), f2h(v.y), f2h(v.z), f2h(v.w));
}

// ---------------------------------------------------------------------------
// Kernel 1: QKV projection.  256 threads / 4 waves (2x2 wave grid), each wave
// owns a 64x64 sub-tile (acc[4][4]) of the 128x128 tile.  8 ds_read_b128 feed
// 16 MFMA.  BK=32, glds dbuf (1 barrier/iter) + XOR column-group swizzle.
// Q pre-scaled by log2(e)/8.
//   Q,K: [B,H,2048,64] fp16     V: transposed [B,H,64,2048] fp16
// ---------------------------------------------------------------------------
__global__ __launch_bounds__(256, 3) void qkv_gemm(
    const unsigned short* __restrict__ Xb, const unsigned short* __restrict__ Wb,
    const float* __restrict__ bias, unsigned short* __restrict__ Qb,
    unsigned short* __restrict__ Kb, unsigned short* __restrict__ Vt) {
  __shared__ __align__(16) unsigned short A_sh[2][128 * 32];
  __shared__ __align__(16) unsigned short B_sh[2][128 * 32];
  const int n0 = blockIdx.x * 128, m0 = blockIdx.y * 128;
  const int tid = threadIdx.x, lane = tid & 63, wave = tid >> 6;  // 0..3
  const int wr = wave >> 1, wc = wave & 1;   // 2x2 wave grid, 64x64 each
  const int lm = lane & 15, lg = lane >> 4;
  const int r4 = lane >> 2;                              // staging row in chunk
  const int sg8 = (((lane & 3) ^ ((r4 >> 1) & 3)) * 8);  // swizzled src colgrp
  const int lgx = (lg ^ ((lm >> 1) & 3)) * 8;            // swizzled read colgrp

  f32x4 acc[4][4] = {};

#define QSTAGE(k0_, b_)                                                       \
  do {                                                                        \
    _Pragma("unroll")                                                         \
    for (int j = 0; j < 2; ++j) {                                             \
      const int chunk = wave * 2 + j;                                         \
      const int row = chunk * 16 + r4;                                        \
      GLOAD_LDS16(Xb + (size_t)(m0 + row) * 1024 + (k0_) + sg8,               \
                  &A_sh[b_][chunk * 512]);                                    \
      GLOAD_LDS16(Wb + (size_t)(n0 + row) * 1024 + (k0_) + sg8,               \
                  &B_sh[b_][chunk * 512]);                                    \
    }                                                                         \
  } while (0)

  QSTAGE(0, 0);

  for (int it = 0; it < 32; ++it) {
    const int cur = it & 1;
    __syncthreads();  // buf[cur] ready; buf[cur^1] free
    if (it < 31) QSTAGE((it + 1) * 32, cur ^ 1);  // fly during compute

    f16x8 af[4], bfr[4];
#pragma unroll
    for (int mi = 0; mi < 4; ++mi)
      af[mi] = *(const f16x8*)&A_sh[cur][(wr * 64 + mi * 16 + lm) * 32 + lgx];
#pragma unroll
    for (int ni = 0; ni < 4; ++ni)
      bfr[ni] = *(const f16x8*)&B_sh[cur][(wc * 64 + ni * 16 + lm) * 32 + lgx];
    __builtin_amdgcn_s_setprio(1);
#pragma unroll
    for (int mi = 0; mi < 4; ++mi)
#pragma unroll
      for (int ni = 0; ni < 4; ++ni)
        acc[mi][ni] = __builtin_amdgcn_mfma_f32_16x16x32_f16(
            af[mi], bfr[ni], acc[mi][ni], 0, 0, 0);
    __builtin_amdgcn_s_setprio(0);
  }
#undef QSTAGE

  const float qscale = 0.18033688011112042f;  // log2(e)/8  (folded attn scale)
#pragma unroll
  for (int mi = 0; mi < 4; ++mi) {
#pragma unroll
    for (int ni = 0; ni < 4; ++ni) {
      const int gn = n0 + wc * 64 + ni * 16 + lm;
      const float bv = bias[gn];
      const int which = gn >> 10;
      const int h = (gn >> 6) & 15;
      const int hd = gn & 63;
      float v[4];
#pragma unroll
      for (int r = 0; r < 4; ++r) v[r] = acc[mi][ni][r] + bv;
      const int gm0 = m0 + wr * 64 + mi * 16 + lg * 4;
      const int bb = gm0 >> 11;
      const int nq0 = gm0 & 2047;
      if (which == 0) {
        unsigned short* p = Qb + (((size_t)bb * 16 + h) * 2048 + nq0) * 64 + hd;
        p[0] = f2h(v[0] * qscale);   p[64] = f2h(v[1] * qscale);
        p[128] = f2h(v[2] * qscale); p[192] = f2h(v[3] * qscale);
      } else if (which == 1) {
        unsigned short* p = Kb + (((size_t)bb * 16 + h) * 2048 + nq0) * 64 + hd;
        p[0] = f2h(v[0]);   p[64] = f2h(v[1]);
        p[128] = f2h(v[2]); p[192] = f2h(v[3]);
      } else {
        *(ushort4*)(Vt + (((size_t)bb * 16 + h) * 64 + hd) * 2048 + nq0) =
            make_ushort4(f2h(v[0]), f2h(v[1]), f2h(v[2]), f2h(v[3]));
      }
    }
  }
}

// ---------------------------------------------------------------------------
// Kernel 2: flash attention.  KV-split (verified round 6) + NEW this round:
//  (a) ones-column lsum: o_ones[mi] = mfma(pa, 1, o_ones[mi]) replaces the 16
//      per-iter lsum adds AND the end shfl-reduce (denominator lands in the
//      same row layout as O, replicated across lm); denominator now sums the
//      f16-rounded P used in the numerator (rounding cancels in the ratio).
//  (b) v_cvt_pkrtz_f16_f32 packing (1 op / 2 values, was 3).
//  (c) s_setprio(1) around both MFMA clusters (T5).
// Staging/swizzle/merge structure byte-identical to the round-6 kernel.
// ---------------------------------------------------------------------------
__global__ __launch_bounds__(512, 4) void attn_kernel(
    const unsigned short* __restrict__ Qb, const unsigned short* __restrict__ Kb,
    const unsigned short* __restrict__ Vt, unsigned short* __restrict__ Ob) {
  __shared__ __align__(16) unsigned short K_sh[2][2][64 * 32];
  __shared__ __align__(16) unsigned short V_sh[2][2][64 * 32];
  __shared__ __align__(16) f32x4 Om[4][5][64];   // 20 KB merge (ni 0..3 + ones)
  const int bh = blockIdx.y, q0 = blockIdx.x * 128;
  const size_t base = (size_t)bh * (2048 * 64);
  const unsigned short* Qp = Qb + base;
  const unsigned short* Kp = Kb + base;
  const unsigned short* Vp = Vt + base;  // [64][2048]
  const int tid = threadIdx.x, lane = tid & 63, wave = tid >> 6;  // 0..7
  const int lm = lane & 15, lg = lane >> 4;
  const int r4 = lane >> 2;
  const int sg8 = (((lane & 3) ^ ((r4 >> 1) & 3)) * 8);
  const int lgx = (lg ^ ((lm >> 1) & 3)) * 8;

  const int qg = wave >> 1;      // 0..3 : q-group (32 rows)
  const int khalf = wave & 1;    // 0/1  : kv half within each 64-tile

  f16x8 vones;
#pragma unroll
  for (int j = 0; j < 8; ++j) vones[j] = (_Float16)1.0f;

  f16x8 qf[2][2];
#pragma unroll
  for (int mi = 0; mi < 2; ++mi)
#pragma unroll
    for (int kc = 0; kc < 2; ++kc)
      qf[mi][kc] = *(const f16x8*)(Qp +
          (size_t)(q0 + qg * 32 + mi * 16 + lm) * 64 + kc * 32 + lg * 8);

  f32x4 o[2][4] = {};
  f32x4 o_ones[2] = {};

  const bool isV = wave >= 4;
  const int plane = wave & 1;
  const int half = (wave >> 1) & 1;

#define STAGE(kt_, b_)                                                        \
  do {                                                                        \
    if (!isV) {                                                               \
      _Pragma("unroll")                                                       \
      for (int qv = 0; qv < 2; ++qv)                                          \
        GLOAD_LDS16(Kp + (size_t)((kt_) * 64 + half * 32 + qv * 16 + r4) * 64 \
                        + plane * 32 + sg8,                                   \
                    &K_sh[b_][plane][(half * 2 + qv) * 512]);                 \
    } else {                                                                  \
      _Pragma("unroll")                                                       \
      for (int qv = 0; qv < 2; ++qv)                                          \
        GLOAD_LDS16(Vp + (size_t)(half * 32 + qv * 16 + r4) * 2048 +          \
                        (kt_) * 64 + plane * 32 + sg8,                        \
                    &V_sh[b_][plane][(half * 2 + qv) * 512]);                 \
    }                                                                         \
  } while (0)

  STAGE(0, 0);

  for (int kt = 0; kt < 32; ++kt) {
    const int cur = kt & 1;
    __syncthreads();
    if (kt < 31) STAGE(kt + 1, cur ^ 1);

    // ---- swapped QK^T on this wave's kv half:
    // lane holds P[q = q0+qg*32+mi*16+lm][k = khalf*32 + ni*16 + lg*4 + r]
    f32x4 s[2][2] = {};
#pragma unroll
    for (int kc = 0; kc < 2; ++kc) {
#pragma unroll
      for (int ni = 0; ni < 2; ++ni) {
        const f16x8 kf = *(const f16x8*)
            &K_sh[cur][kc][(khalf * 32 + ni * 16 + lm) * 32 + lgx];
        __builtin_amdgcn_s_setprio(1);
        s[0][ni] = __builtin_amdgcn_mfma_f32_16x16x32_f16(
            kf, qf[0][kc], s[0][ni], 0, 0, 0);
        s[1][ni] = __builtin_amdgcn_mfma_f32_16x16x32_f16(
            kf, qf[1][kc], s[1][ni], 0, 0, 0);
        __builtin_amdgcn_s_setprio(0);
      }
    }

    // ---- exp2 + packed-RTZ: Wp_[mi][ni][w] = f16x2(p[2w], p[2w+1]) ----
    unsigned int Wp_[2][2][2];
#pragma unroll
    for (int mi = 0; mi < 2; ++mi)
#pragma unroll
      for (int ni = 0; ni < 2; ++ni) {
        const float p0 = EXP2(s[mi][ni][0]), p1 = EXP2(s[mi][ni][1]);
        const float p2 = EXP2(s[mi][ni][2]), p3 = EXP2(s[mi][ni][3]);
        Wp_[mi][ni][0] = pkrtz(p0, p1);
        Wp_[mi][ni][1] = pkrtz(p2, p3);
      }

    // ---- V fragments for this wave's kv half (4 reads, reused by both mi)
    f16x8 vb[4];
#pragma unroll
    for (int ni = 0; ni < 4; ++ni)
      vb[ni] = *(const f16x8*)&V_sh[cur][khalf][(ni * 16 + lm) * 32 + lgx];

    // ---- in-register P -> PV A-fragment via permlane swaps (K=32) ----
#pragma unroll
    for (int mi = 0; mi < 2; ++mi) {
      auto t0 = __builtin_amdgcn_permlane32_swap(Wp_[mi][0][0], Wp_[mi][1][0],
                                                 false, false);
      auto u0 = __builtin_amdgcn_permlane16_swap(t0[0], t0[1], false, false);
      auto t1 = __builtin_amdgcn_permlane32_swap(Wp_[mi][0][1], Wp_[mi][1][1],
                                                 false, false);
      auto u1 = __builtin_amdgcn_permlane16_swap(t1[0], t1[1], false, false);
      union { unsigned int u[4]; f16x8 v; } pa;
      pa.u[0] = u0[0];  // k = lg*8 + {0,1}
      pa.u[1] = u1[0];  // k = lg*8 + {2,3}
      pa.u[2] = u0[1];  // k = lg*8 + {4,5}
      pa.u[3] = u1[1];  // k = lg*8 + {6,7}
      __builtin_amdgcn_s_setprio(1);
#pragma unroll
      for (int ni = 0; ni < 4; ++ni)
        o[mi][ni] = __builtin_amdgcn_mfma_f32_16x16x32_f16(
            pa.v, vb[ni], o[mi][ni], 0, 0, 0);
      o_ones[mi] = __builtin_amdgcn_mfma_f32_16x16x32_f16(
          pa.v, vones, o_ones[mi], 0, 0, 0);
      __builtin_amdgcn_s_setprio(0);
    }
  }
#undef STAGE

  // ---- merge the two kv-halves via dedicated LDS, one mi-pass at a time ----
  const int b = bh >> 4, h = bh & 15;
#pragma unroll
  for (int mi = 0; mi < 2; ++mi) {
    __syncthreads();
    if (khalf == 1) {
#pragma unroll
      for (int ni = 0; ni < 4; ++ni) Om[qg][ni][lane] = o[mi][ni];
      Om[qg][4][lane] = o_ones[mi];
    }
    __syncthreads();
    if (khalf == 0) {
#pragma unroll
      for (int ni = 0; ni < 4; ++ni) {
        const f32x4 t = Om[qg][ni][lane];
        o[mi][ni][0] += t[0]; o[mi][ni][1] += t[1];
        o[mi][ni][2] += t[2]; o[mi][ni][3] += t[3];
      }
      const f32x4 t4 = Om[qg][4][lane];
#pragma unroll
      for (int r = 0; r < 4; ++r) {
        const float inv = 1.0f / (o_ones[mi][r] + t4[r]);
        const int nq = q0 + qg * 32 + mi * 16 + lg * 4 + r;
        unsigned short* p = Ob + ((size_t)(b * 2048 + nq) * 16 + h) * 64 + lm;
        p[0] = f2h(o[mi][0][r] * inv);
        p[16] = f2h(o[mi][1][r] * inv);
        p[32] = f2h(o[mi][2][r] * inv);
        p[48] = f2h(o[mi][3][r] * inv);
      }
    }
  }
}

// ---------------------------------------------------------------------------
// Kernel 3: output projection, BK=32, 64x128 tile, fp16 MFMA.
// (round-10 version: dbuf async staging + XOR swizzle)
// ---------------------------------------------------------------------------
__global__ __launch_bounds__(256) void proj_gemm(
    const unsigned short* __restrict__ A, const unsigned short* __restrict__ Wb,
    const float* __restrict__ bias, float* __restrict__ Out) {
  __shared__ __align__(16) unsigned short A_sh[2][64 * 32];
  __shared__ __align__(16) unsigned short B_sh[2][128 * 32];
  const int n0 = blockIdx.x * 128, m0 = blockIdx.y * 64;
  const int tid = threadIdx.x, lane = tid & 63, wave = tid >> 6;
  const int wr = wave >> 1, wc = wave & 1, lm = lane & 15, lg = lane >> 4;
  const int r4 = lane >> 2;
  const int sg8 = (((lane & 3) ^ ((r4 >> 1) & 3)) * 8);
  const int lgx = (lg ^ ((lm >> 1) & 3)) * 8;

  f32x4 acc[2][4] = {};

#define PSTAGE(k0_, b_)                                                       \
  do {                                                                        \
    {                                                                         \
      const int row = wave * 16 + r4;                                         \
      GLOAD_LDS16(A + (size_t)(m0 + row) * 1024 + (k0_) + sg8,                \
                  &A_sh[b_][wave * 512]);                                     \
    }                                                                         \
    _Pragma("unroll")                                                         \
    for (int j = 0; j < 2; ++j) {                                             \
      const int chunk = wave * 2 + j;                                         \
      const int row = chunk * 16 + r4;                                        \
      GLOAD_LDS16(Wb + (size_t)(n0 + row) * 1024 + (k0_) + sg8,               \
                  &B_sh[b_][chunk * 512]);                                    \
    }                                                                         \
  } while (0)

  PSTAGE(0, 0);

  for (int it = 0; it < 32; ++it) {
    const int cur = it & 1;
    __syncthreads();
    if (it < 31) PSTAGE((it + 1) * 32, cur ^ 1);

    f16x8 af[2], bfr[4];
#pragma unroll
    for (int mi = 0; mi < 2; ++mi)
      af[mi] = *(const f16x8*)&A_sh[cur][(wr * 32 + mi * 16 + lm) * 32 + lgx];
#pragma unroll
    for (int ni = 0; ni < 4; ++ni)
      bfr[ni] = *(const f16x8*)&B_sh[cur][(wc * 64 + ni * 16 + lm) * 32 + lgx];
#pragma unroll
    for (int mi = 0; mi < 2; ++mi)
#pragma unroll
      for (int ni = 0; ni < 4; ++ni)
        acc[mi][ni] = __builtin_amdgcn_mfma_f32_16x16x32_f16(
            af[mi], bfr[ni], acc[mi][ni], 0, 0, 0);
  }
#undef PSTAGE

#pragma unroll
  for (int mi = 0; mi < 2; ++mi)
#pragma unroll
    for (int ni = 0; ni < 4; ++ni) {
      const int gn = n0 + wc * 64 + ni * 16 + lm;
      const float bv = bias[gn];
#pragma unroll
      for (int r = 0; r < 4; ++r) {
        const int gm = m0 + wr * 32 + mi * 16 + lg * 4 + r;
        Out[(size_t)gm * 1024 + gn] = acc[mi][ni][r] + bv;
      }
    }
}

extern "C" void kernel_launch(void* const* d_in, const int* in_sizes, int n_in,
                              void* d_out, int out_size, void* d_ws, size_t ws_size,
                              hipStream_t stream) {
  const float* x      = (const float*)d_in[0];
  const float* W_qkv  = (const float*)d_in[1];
  const float* b_qkv  = (const float*)d_in[2];
  const float* W_proj = (const float*)d_in[3];
  const float* b_proj = (const float*)d_in[4];
  float* out = (float*)d_out;

  unsigned short* Qb  = (unsigned short*)d_ws;
  unsigned short* Kb  = Qb + 4194304;
  unsigned short* Vt  = Kb + 4194304;
  unsigned short* Ao  = Vt + 4194304;
  unsigned short* Xb  = Ao + 4194304;
  unsigned short* Wqb = Xb + 4194304;
  unsigned short* Wpb = Wqb + 3145728;

  cvt_all<<<8192, 256, 0, stream>>>(x, W_qkv, W_proj, Xb, Wqb, Wpb);
  qkv_gemm<<<dim3(24, 32), 256, 0, stream>>>(Xb, Wqb, b_qkv, Qb, Kb, Vt);
  attn_kernel<<<dim3(16, 32), 512, 0, stream>>>(Qb, Kb, Vt, Ao);
  proj_gemm<<<dim3(8, 64), 256, 0, stream>>>(Ao, Wpb, b_proj, out);
}

// Round 8
// 182.093 us; speedup vs baseline: 1.0986x; 1.0104x over previous
//
#include <hip/hip_runtime.h>

typedef _Float16 f16x8 __attribute__((ext_vector_type(8)));
typedef __attribute__((ext_vector_type(4))) float f32x4;

// fp32 -> fp16 (RNE) bit pattern
static __device__ __forceinline__ unsigned short f2h(float f) {
  return __builtin_bit_cast(unsigned short, (_Float16)f);
}

// pack two fp32 -> one dword of two fp16
static __device__ __forceinline__ unsigned int pk2(float a, float b) {
  return (unsigned int)f2h(a) | ((unsigned int)f2h(b) << 16);
}

// packed RTZ convert (1 VALU op vs 3); numerator/denominator bias cancels
#if __has_builtin(__builtin_amdgcn_cvt_pkrtz)
static __device__ __forceinline__ unsigned int pkrtz(float a, float b) {
  return __builtin_bit_cast(unsigned int, __builtin_amdgcn_cvt_pkrtz(a, b));
}
#else
#define pkrtz pk2
#endif

// raw v_exp_f32 (inputs bounded; fp16 margin absorbs the ~1ulp gap vs libm)
#if __has_builtin(__builtin_amdgcn_exp2f)
#define EXP2(x) __builtin_amdgcn_exp2f(x)
#else
#define EXP2(x) exp2f(x)
#endif

// async global->LDS, 16 B per lane; LDS dst = wave-uniform base + lane*16.
#define GLOAD_LDS16(gp, lp)                                          \
  __builtin_amdgcn_global_load_lds(                                  \
      (const __attribute__((address_space(1))) unsigned int*)(gp),   \
      (__attribute__((address_space(3))) unsigned int*)(lp), 16, 0, 0)

// ---------------------------------------------------------------------------
// Kernel 0: fp32 -> fp16 conversion for X, W_qkv, W_proj (one launch).
// ---------------------------------------------------------------------------
__global__ __launch_bounds__(256) void cvt_all(
    const float* __restrict__ X, const float* __restrict__ Wq,
    const float* __restrict__ Wp, unsigned short* __restrict__ Xb,
    unsigned short* __restrict__ Wqb, unsigned short* __restrict__ Wpb) {
  const int i = blockIdx.x * 256 + threadIdx.x;
  const float4* src;
  unsigned short* dst;
  int off;
  if (i < 1048576) {
    src = (const float4*)X; dst = Xb; off = i;
  } else if (i < 1835008) {
    src = (const float4*)Wq; dst = Wqb; off = i - 1048576;
  } else {
    src = (const float4*)Wp; dst = Wpb; off = i - 1835008;
  }
  const float4 v = src[off];
  *(ushort4*)(dst + (size_t)off * 4) =
      make_ushort4(f2h(v.x), f2h(v.y), f2h(v.z), f2h(v.w));
}

// ---------------------------------------------------------------------------
// Kernel 1: QKV projection.  256 threads / 4 waves (2x2 wave grid), each wave
// owns a 64x64 sub-tile (acc[4][4]) of the 128x128 tile.  8 ds_read_b128 feed
// 16 MFMA.  BK=32, glds dbuf (1 barrier/iter) + XOR column-group swizzle.
// Q pre-scaled by log2(e)/8.
//   Q,K: [B,H,2048,64] fp16     V: transposed [B,H,64,2048] fp16
// ---------------------------------------------------------------------------
__global__ __launch_bounds__(256, 3) void qkv_gemm(
    const unsigned short* __restrict__ Xb, const unsigned short* __restrict__ Wb,
    const float* __restrict__ bias, unsigned short* __restrict__ Qb,
    unsigned short* __restrict__ Kb, unsigned short* __restrict__ Vt) {
  __shared__ __align__(16) unsigned short A_sh[2][128 * 32];
  __shared__ __align__(16) unsigned short B_sh[2][128 * 32];
  const int n0 = blockIdx.x * 128, m0 = blockIdx.y * 128;
  const int tid = threadIdx.x, lane = tid & 63, wave = tid >> 6;  // 0..3
  const int wr = wave >> 1, wc = wave & 1;   // 2x2 wave grid, 64x64 each
  const int lm = lane & 15, lg = lane >> 4;
  const int r4 = lane >> 2;                              // staging row in chunk
  const int sg8 = (((lane & 3) ^ ((r4 >> 1) & 3)) * 8);  // swizzled src colgrp
  const int lgx = (lg ^ ((lm >> 1) & 3)) * 8;            // swizzled read colgrp

  f32x4 acc[4][4] = {};

#define QSTAGE(k0_, b_)                                                       \
  do {                                                                        \
    _Pragma("unroll")                                                         \
    for (int j = 0; j < 2; ++j) {                                             \
      const int chunk = wave * 2 + j;                                         \
      const int row = chunk * 16 + r4;                                        \
      GLOAD_LDS16(Xb + (size_t)(m0 + row) * 1024 + (k0_) + sg8,               \
                  &A_sh[b_][chunk * 512]);                                    \
      GLOAD_LDS16(Wb + (size_t)(n0 + row) * 1024 + (k0_) + sg8,               \
                  &B_sh[b_][chunk * 512]);                                    \
    }                                                                         \
  } while (0)

  QSTAGE(0, 0);

  for (int it = 0; it < 32; ++it) {
    const int cur = it & 1;
    __syncthreads();  // buf[cur] ready; buf[cur^1] free
    if (it < 31) QSTAGE((it + 1) * 32, cur ^ 1);  // fly during compute

    f16x8 af[4], bfr[4];
#pragma unroll
    for (int mi = 0; mi < 4; ++mi)
      af[mi] = *(const f16x8*)&A_sh[cur][(wr * 64 + mi * 16 + lm) * 32 + lgx];
#pragma unroll
    for (int ni = 0; ni < 4; ++ni)
      bfr[ni] = *(const f16x8*)&B_sh[cur][(wc * 64 + ni * 16 + lm) * 32 + lgx];
    __builtin_amdgcn_s_setprio(1);
#pragma unroll
    for (int mi = 0; mi < 4; ++mi)
#pragma unroll
      for (int ni = 0; ni < 4; ++ni)
        acc[mi][ni] = __builtin_amdgcn_mfma_f32_16x16x32_f16(
            af[mi], bfr[ni], acc[mi][ni], 0, 0, 0);
    __builtin_amdgcn_s_setprio(0);
  }
#undef QSTAGE

  const float qscale = 0.18033688011112042f;  // log2(e)/8  (folded attn scale)
#pragma unroll
  for (int mi = 0; mi < 4; ++mi) {
#pragma unroll
    for (int ni = 0; ni < 4; ++ni) {
      const int gn = n0 + wc * 64 + ni * 16 + lm;
      const float bv = bias[gn];
      const int which = gn >> 10;
      const int h = (gn >> 6) & 15;
      const int hd = gn & 63;
      float v[4];
#pragma unroll
      for (int r = 0; r < 4; ++r) v[r] = acc[mi][ni][r] + bv;
      const int gm0 = m0 + wr * 64 + mi * 16 + lg * 4;
      const int bb = gm0 >> 11;
      const int nq0 = gm0 & 2047;
      if (which == 0) {
        unsigned short* p = Qb + (((size_t)bb * 16 + h) * 2048 + nq0) * 64 + hd;
        p[0] = f2h(v[0] * qscale);   p[64] = f2h(v[1] * qscale);
        p[128] = f2h(v[2] * qscale); p[192] = f2h(v[3] * qscale);
      } else if (which == 1) {
        unsigned short* p = Kb + (((size_t)bb * 16 + h) * 2048 + nq0) * 64 + hd;
        p[0] = f2h(v[0]);   p[64] = f2h(v[1]);
        p[128] = f2h(v[2]); p[192] = f2h(v[3]);
      } else {
        *(ushort4*)(Vt + (((size_t)bb * 16 + h) * 64 + hd) * 2048 + nq0) =
            make_ushort4(f2h(v[0]), f2h(v[1]), f2h(v[2]), f2h(v[3]));
      }
    }
  }
}

// ---------------------------------------------------------------------------
// Kernel 2: flash attention.  NEW this round: QBLK=256, 1024 threads /
// 16 waves (8 q-groups x 2 kv-halves) -> grid (8,32) = 256 blocks = 1/CU,
// 4 waves/SIMD (was 2.75).  Rationale: round-7 counters show no pipe >45%
// (LDS 42%, VALU 39%, MFMA 30%) => dependency-latency-bound; the fix is
// concurrency, not traffic.  Per-wave inner loop (32q x 32kv, swapped QK^T,
// permlane repack, ones-column lsum, pkrtz, setprio) byte-identical to the
// verified round-7 kernel.  Staging: 16 waves x 1 GLOAD/iter (same 16KB/tile,
// same swizzle).  Merge buffer Om[8][5].  LDS 72KB, 1 block/CU.
// ---------------------------------------------------------------------------
__global__ __launch_bounds__(1024, 4) void attn_kernel(
    const unsigned short* __restrict__ Qb, const unsigned short* __restrict__ Kb,
    const unsigned short* __restrict__ Vt, unsigned short* __restrict__ Ob) {
  __shared__ __align__(16) unsigned short K_sh[2][2][64 * 32];
  __shared__ __align__(16) unsigned short V_sh[2][2][64 * 32];
  __shared__ __align__(16) f32x4 Om[8][5][64];   // 40 KB merge (ni 0..3 + ones)
  const int bh = blockIdx.y, q0 = blockIdx.x * 256;
  const size_t base = (size_t)bh * (2048 * 64);
  const unsigned short* Qp = Qb + base;
  const unsigned short* Kp = Kb + base;
  const unsigned short* Vp = Vt + base;  // [64][2048]
  const int tid = threadIdx.x, lane = tid & 63, wave = tid >> 6;  // 0..15
  const int lm = lane & 15, lg = lane >> 4;
  const int r4 = lane >> 2;
  const int sg8 = (((lane & 3) ^ ((r4 >> 1) & 3)) * 8);
  const int lgx = (lg ^ ((lm >> 1) & 3)) * 8;

  const int qg = wave >> 1;      // 0..7 : q-group (32 rows)
  const int khalf = wave & 1;    // 0/1  : kv half within each 64-tile

  f16x8 vones;
#pragma unroll
  for (int j = 0; j < 8; ++j) vones[j] = (_Float16)1.0f;

  f16x8 qf[2][2];
#pragma unroll
  for (int mi = 0; mi < 2; ++mi)
#pragma unroll
    for (int kc = 0; kc < 2; ++kc)
      qf[mi][kc] = *(const f16x8*)(Qp +
          (size_t)(q0 + qg * 32 + mi * 16 + lm) * 64 + kc * 32 + lg * 8);

  f32x4 o[2][4] = {};
  f32x4 o_ones[2] = {};

  // staging roles: 16 waves, 1 GLOAD each (8 K-chunks + 8 V-chunks of 1KB)
  const bool isV = wave >= 8;
  const int sw = wave & 7;
  const int plane = sw & 1;
  const int chunk = sw >> 1;     // 0..3 : 16-row group within the plane

#define STAGE(kt_, b_)                                                        \
  do {                                                                        \
    if (!isV) {                                                               \
      GLOAD_LDS16(Kp + (size_t)((kt_) * 64 + chunk * 16 + r4) * 64 +          \
                      plane * 32 + sg8,                                       \
                  &K_sh[b_][plane][chunk * 512]);                             \
    } else {                                                                  \
      GLOAD_LDS16(Vp + (size_t)(chunk * 16 + r4) * 2048 +                     \
                      (kt_) * 64 + plane * 32 + sg8,                          \
                  &V_sh[b_][plane][chunk * 512]);                             \
    }                                                                         \
  } while (0)

  STAGE(0, 0);

  for (int kt = 0; kt < 32; ++kt) {
    const int cur = kt & 1;
    __syncthreads();
    if (kt < 31) STAGE(kt + 1, cur ^ 1);

    // ---- swapped QK^T on this wave's kv half:
    // lane holds P[q = q0+qg*32+mi*16+lm][k = khalf*32 + ni*16 + lg*4 + r]
    f32x4 s[2][2] = {};
#pragma unroll
    for (int kc = 0; kc < 2; ++kc) {
#pragma unroll
      for (int ni = 0; ni < 2; ++ni) {
        const f16x8 kf = *(const f16x8*)
            &K_sh[cur][kc][(khalf * 32 + ni * 16 + lm) * 32 + lgx];
        __builtin_amdgcn_s_setprio(1);
        s[0][ni] = __builtin_amdgcn_mfma_f32_16x16x32_f16(
            kf, qf[0][kc], s[0][ni], 0, 0, 0);
        s[1][ni] = __builtin_amdgcn_mfma_f32_16x16x32_f16(
            kf, qf[1][kc], s[1][ni], 0, 0, 0);
        __builtin_amdgcn_s_setprio(0);
      }
    }

    // ---- exp2 + packed-RTZ: Wp_[mi][ni][w] = f16x2(p[2w], p[2w+1]) ----
    unsigned int Wp_[2][2][2];
#pragma unroll
    for (int mi = 0; mi < 2; ++mi)
#pragma unroll
      for (int ni = 0; ni < 2; ++ni) {
        const float p0 = EXP2(s[mi][ni][0]), p1 = EXP2(s[mi][ni][1]);
        const float p2 = EXP2(s[mi][ni][2]), p3 = EXP2(s[mi][ni][3]);
        Wp_[mi][ni][0] = pkrtz(p0, p1);
        Wp_[mi][ni][1] = pkrtz(p2, p3);
      }

    // ---- V fragments for this wave's kv half (4 reads, reused by both mi)
    f16x8 vb[4];
#pragma unroll
    for (int ni = 0; ni < 4; ++ni)
      vb[ni] = *(const f16x8*)&V_sh[cur][khalf][(ni * 16 + lm) * 32 + lgx];

    // ---- in-register P -> PV A-fragment via permlane swaps (K=32) ----
#pragma unroll
    for (int mi = 0; mi < 2; ++mi) {
      auto t0 = __builtin_amdgcn_permlane32_swap(Wp_[mi][0][0], Wp_[mi][1][0],
                                                 false, false);
      auto u0 = __builtin_amdgcn_permlane16_swap(t0[0], t0[1], false, false);
      auto t1 = __builtin_amdgcn_permlane32_swap(Wp_[mi][0][1], Wp_[mi][1][1],
                                                 false, false);
      auto u1 = __builtin_amdgcn_permlane16_swap(t1[0], t1[1], false, false);
      union { unsigned int u[4]; f16x8 v; } pa;
      pa.u[0] = u0[0];  // k = lg*8 + {0,1}
      pa.u[1] = u1[0];  // k = lg*8 + {2,3}
      pa.u[2] = u0[1];  // k = lg*8 + {4,5}
      pa.u[3] = u1[1];  // k = lg*8 + {6,7}
      __builtin_amdgcn_s_setprio(1);
#pragma unroll
      for (int ni = 0; ni < 4; ++ni)
        o[mi][ni] = __builtin_amdgcn_mfma_f32_16x16x32_f16(
            pa.v, vb[ni], o[mi][ni], 0, 0, 0);
      o_ones[mi] = __builtin_amdgcn_mfma_f32_16x16x32_f16(
          pa.v, vones, o_ones[mi], 0, 0, 0);
      __builtin_amdgcn_s_setprio(0);
    }
  }
#undef STAGE

  // ---- merge the two kv-halves via dedicated LDS, one mi-pass at a time ----
  const int b = bh >> 4, h = bh & 15;
#pragma unroll
  for (int mi = 0; mi < 2; ++mi) {
    __syncthreads();
    if (khalf == 1) {
#pragma unroll
      for (int ni = 0; ni < 4; ++ni) Om[qg][ni][lane] = o[mi][ni];
      Om[qg][4][lane] = o_ones[mi];
    }
    __syncthreads();
    if (khalf == 0) {
#pragma unroll
      for (int ni = 0; ni < 4; ++ni) {
        const f32x4 t = Om[qg][ni][lane];
        o[mi][ni][0] += t[0]; o[mi][ni][1] += t[1];
        o[mi][ni][2] += t[2]; o[mi][ni][3] += t[3];
      }
      const f32x4 t4 = Om[qg][4][lane];
#pragma unroll
      for (int r = 0; r < 4; ++r) {
        const float inv = 1.0f / (o_ones[mi][r] + t4[r]);
        const int nq = q0 + qg * 32 + mi * 16 + lg * 4 + r;
        unsigned short* p = Ob + ((size_t)(b * 2048 + nq) * 16 + h) * 64 + lm;
        p[0] = f2h(o[mi][0][r] * inv);
        p[16] = f2h(o[mi][1][r] * inv);
        p[32] = f2h(o[mi][2][r] * inv);
        p[48] = f2h(o[mi][3][r] * inv);
      }
    }
  }
}

// ---------------------------------------------------------------------------
// Kernel 3: output projection, BK=32, 64x128 tile, fp16 MFMA.
// (round-10 version: dbuf async staging + XOR swizzle)
// ---------------------------------------------------------------------------
__global__ __launch_bounds__(256) void proj_gemm(
    const unsigned short* __restrict__ A, const unsigned short* __restrict__ Wb,
    const float* __restrict__ bias, float* __restrict__ Out) {
  __shared__ __align__(16) unsigned short A_sh[2][64 * 32];
  __shared__ __align__(16) unsigned short B_sh[2][128 * 32];
  const int n0 = blockIdx.x * 128, m0 = blockIdx.y * 64;
  const int tid = threadIdx.x, lane = tid & 63, wave = tid >> 6;
  const int wr = wave >> 1, wc = wave & 1, lm = lane & 15, lg = lane >> 4;
  const int r4 = lane >> 2;
  const int sg8 = (((lane & 3) ^ ((r4 >> 1) & 3)) * 8);
  const int lgx = (lg ^ ((lm >> 1) & 3)) * 8;

  f32x4 acc[2][4] = {};

#define PSTAGE(k0_, b_)                                                       \
  do {                                                                        \
    {                                                                         \
      const int row = wave * 16 + r4;                                         \
      GLOAD_LDS16(A + (size_t)(m0 + row) * 1024 + (k0_) + sg8,                \
                  &A_sh[b_][wave * 512]);                                     \
    }                                                                         \
    _Pragma("unroll")                                                         \
    for (int j = 0; j < 2; ++j) {                                             \
      const int chunk = wave * 2 + j;                                         \
      const int row = chunk * 16 + r4;                                        \
      GLOAD_LDS16(Wb + (size_t)(n0 + row) * 1024 + (k0_) + sg8,               \
                  &B_sh[b_][chunk * 512]);                                    \
    }                                                                         \
  } while (0)

  PSTAGE(0, 0);

  for (int it = 0; it < 32; ++it) {
    const int cur = it & 1;
    __syncthreads();
    if (it < 31) PSTAGE((it + 1) * 32, cur ^ 1);

    f16x8 af[2], bfr[4];
#pragma unroll
    for (int mi = 0; mi < 2; ++mi)
      af[mi] = *(const f16x8*)&A_sh[cur][(wr * 32 + mi * 16 + lm) * 32 + lgx];
#pragma unroll
    for (int ni = 0; ni < 4; ++ni)
      bfr[ni] = *(const f16x8*)&B_sh[cur][(wc * 64 + ni * 16 + lm) * 32 + lgx];
#pragma unroll
    for (int mi = 0; mi < 2; ++mi)
#pragma unroll
      for (int ni = 0; ni < 4; ++ni)
        acc[mi][ni] = __builtin_amdgcn_mfma_f32_16x16x32_f16(
            af[mi], bfr[ni], acc[mi][ni], 0, 0, 0);
  }
#undef PSTAGE

#pragma unroll
  for (int mi = 0; mi < 2; ++mi)
#pragma unroll
    for (int ni = 0; ni < 4; ++ni) {
      const int gn = n0 + wc * 64 + ni * 16 + lm;
      const float bv = bias[gn];
#pragma unroll
      for (int r = 0; r < 4; ++r) {
        const int gm = m0 + wr * 32 + mi * 16 + lg * 4 + r;
        Out[(size_t)gm * 1024 + gn] = acc[mi][ni][r] + bv;
      }
    }
}

extern "C" void kernel_launch(void* const* d_in, const int* in_sizes, int n_in,
                              void* d_out, int out_size, void* d_ws, size_t ws_size,
                              hipStream_t stream) {
  const float* x      = (const float*)d_in[0];
  const float* W_qkv  = (const float*)d_in[1];
  const float* b_qkv  = (const float*)d_in[2];
  const float* W_proj = (const float*)d_in[3];
  const float* b_proj = (const float*)d_in[4];
  float* out = (float*)d_out;

  unsigned short* Qb  = (unsigned short*)d_ws;
  unsigned short* Kb  = Qb + 4194304;
  unsigned short* Vt  = Kb + 4194304;
  unsigned short* Ao  = Vt + 4194304;
  unsigned short* Xb  = Ao + 4194304;
  unsigned short* Wqb = Xb + 4194304;
  unsigned short* Wpb = Wqb + 3145728;

  cvt_all<<<8192, 256, 0, stream>>>(x, W_qkv, W_proj, Xb, Wqb, Wpb);
  qkv_gemm<<<dim3(24, 32), 256, 0, stream>>>(Xb, Wqb, b_qkv, Qb, Kb, Vt);
  attn_kernel<<<dim3(8, 32), 1024, 0, stream>>>(Qb, Kb, Vt, Ao);
  proj_gemm<<<dim3(8, 64), 256, 0, stream>>>(Ao, Wpb, b_proj, out);
}

// Round 10
// 179.250 us; speedup vs baseline: 1.1160x; 1.0159x over previous
//
#include <hip/hip_runtime.h>

typedef _Float16 f16x8 __attribute__((ext_vector_type(8)));
typedef __attribute__((ext_vector_type(4))) float f32x4;

// fp32 -> fp16 (RNE) bit pattern
static __device__ __forceinline__ unsigned short f2h(float f) {
  return __builtin_bit_cast(unsigned short, (_Float16)f);
}

// pack two fp32 -> one dword of two fp16
static __device__ __forceinline__ unsigned int pk2(float a, float b) {
  return (unsigned int)f2h(a) | ((unsigned int)f2h(b) << 16);
}

// packed RTZ convert (1 VALU op vs 3); numerator/denominator bias cancels
#if __has_builtin(__builtin_amdgcn_cvt_pkrtz)
static __device__ __forceinline__ unsigned int pkrtz(float a, float b) {
  return __builtin_bit_cast(unsigned int, __builtin_amdgcn_cvt_pkrtz(a, b));
}
#else
#define pkrtz pk2
#endif

// raw v_exp_f32 (inputs bounded; fp16 margin absorbs the ~1ulp gap vs libm)
#if __has_builtin(__builtin_amdgcn_exp2f)
#define EXP2(x) __builtin_amdgcn_exp2f(x)
#else
#define EXP2(x) exp2f(x)
#endif

// async global->LDS, 16 B per lane; LDS dst = wave-uniform base + lane*16.
#define GLOAD_LDS16(gp, lp)                                          \
  __builtin_amdgcn_global_load_lds(                                  \
      (const __attribute__((address_space(1))) unsigned int*)(gp),   \
      (__attribute__((address_space(3))) unsigned int*)(lp), 16, 0, 0)

// ---------------------------------------------------------------------------
// Kernel 0: fp32 -> fp16 conversion for X, W_qkv, W_proj (one launch).
// ---------------------------------------------------------------------------
__global__ __launch_bounds__(256) void cvt_all(
    const float* __restrict__ X, const float* __restrict__ Wq,
    const float* __restrict__ Wp, unsigned short* __restrict__ Xb,
    unsigned short* __restrict__ Wqb, unsigned short* __restrict__ Wpb) {
  const int i = blockIdx.x * 256 + threadIdx.x;
  const float4* src;
  unsigned short* dst;
  int off;
  if (i < 1048576) {
    src = (const float4*)X; dst = Xb; off = i;
  } else if (i < 1835008) {
    src = (const float4*)Wq; dst = Wqb; off = i - 1048576;
  } else {
    src = (const float4*)Wp; dst = Wpb; off = i - 1835008;
  }
  const float4 v = src[off];
  *(ushort4*)(dst + (size_t)off * 4) =
      make_ushort4(f2h(v.x), f2h(v.y), f2h(v.z), f2h(v.w));
}

// ---------------------------------------------------------------------------
// Kernel 1: QKV projection.  256 threads / 4 waves (2x2 wave grid), each wave
// owns a 64x64 sub-tile (acc[4][4]) of the 128x128 tile.  8 ds_read_b128 feed
// 16 MFMA.  BK=32, glds dbuf (1 barrier/iter) + XOR column-group swizzle.
// launch_bounds (256,4) occupancy probe.  Q pre-scaled by log2(e)/8.
//   Q,K: [B,H,2048,64] fp16     V: transposed [B,H,64,2048] fp16
// ---------------------------------------------------------------------------
__global__ __launch_bounds__(256, 4) void qkv_gemm(
    const unsigned short* __restrict__ Xb, const unsigned short* __restrict__ Wb,
    const float* __restrict__ bias, unsigned short* __restrict__ Qb,
    unsigned short* __restrict__ Kb, unsigned short* __restrict__ Vt) {
  __shared__ __align__(16) unsigned short A_sh[2][128 * 32];
  __shared__ __align__(16) unsigned short B_sh[2][128 * 32];
  const int n0 = blockIdx.x * 128, m0 = blockIdx.y * 128;
  const int tid = threadIdx.x, lane = tid & 63, wave = tid >> 6;  // 0..3
  const int wr = wave >> 1, wc = wave & 1;   // 2x2 wave grid, 64x64 each
  const int lm = lane & 15, lg = lane >> 4;
  const int r4 = lane >> 2;                              // staging row in chunk
  const int sg8 = (((lane & 3) ^ ((r4 >> 1) & 3)) * 8);  // swizzled src colgrp
  const int lgx = (lg ^ ((lm >> 1) & 3)) * 8;            // swizzled read colgrp

  f32x4 acc[4][4] = {};

#define QSTAGE(k0_, b_)                                                       \
  do {                                                                        \
    _Pragma("unroll")                                                         \
    for (int j = 0; j < 2; ++j) {                                             \
      const int chunk = wave * 2 + j;                                         \
      const int row = chunk * 16 + r4;                                        \
      GLOAD_LDS16(Xb + (size_t)(m0 + row) * 1024 + (k0_) + sg8,               \
                  &A_sh[b_][chunk * 512]);                                    \
      GLOAD_LDS16(Wb + (size_t)(n0 + row) * 1024 + (k0_) + sg8,               \
                  &B_sh[b_][chunk * 512]);                                    \
    }                                                                         \
  } while (0)

  QSTAGE(0, 0);

  for (int it = 0; it < 32; ++it) {
    const int cur = it & 1;
    __syncthreads();  // buf[cur] ready; buf[cur^1] free
    if (it < 31) QSTAGE((it + 1) * 32, cur ^ 1);  // fly during compute

    f16x8 af[4], bfr[4];
#pragma unroll
    for (int mi = 0; mi < 4; ++mi)
      af[mi] = *(const f16x8*)&A_sh[cur][(wr * 64 + mi * 16 + lm) * 32 + lgx];
#pragma unroll
    for (int ni = 0; ni < 4; ++ni)
      bfr[ni] = *(const f16x8*)&B_sh[cur][(wc * 64 + ni * 16 + lm) * 32 + lgx];
    __builtin_amdgcn_s_setprio(1);
#pragma unroll
    for (int mi = 0; mi < 4; ++mi)
#pragma unroll
      for (int ni = 0; ni < 4; ++ni)
        acc[mi][ni] = __builtin_amdgcn_mfma_f32_16x16x32_f16(
            af[mi], bfr[ni], acc[mi][ni], 0, 0, 0);
    __builtin_amdgcn_s_setprio(0);
  }
#undef QSTAGE

  const float qscale = 0.18033688011112042f;  // log2(e)/8  (folded attn scale)
#pragma unroll
  for (int mi = 0; mi < 4; ++mi) {
#pragma unroll
    for (int ni = 0; ni < 4; ++ni) {
      const int gn = n0 + wc * 64 + ni * 16 + lm;
      const float bv = bias[gn];
      const int which = gn >> 10;
      const int h = (gn >> 6) & 15;
      const int hd = gn & 63;
      float v[4];
#pragma unroll
      for (int r = 0; r < 4; ++r) v[r] = acc[mi][ni][r] + bv;
      const int gm0 = m0 + wr * 64 + mi * 16 + lg * 4;
      const int bb = gm0 >> 11;
      const int nq0 = gm0 & 2047;
      if (which == 0) {
        unsigned short* p = Qb + (((size_t)bb * 16 + h) * 2048 + nq0) * 64 + hd;
        p[0] = f2h(v[0] * qscale);   p[64] = f2h(v[1] * qscale);
        p[128] = f2h(v[2] * qscale); p[192] = f2h(v[3] * qscale);
      } else if (which == 1) {
        unsigned short* p = Kb + (((size_t)bb * 16 + h) * 2048 + nq0) * 64 + hd;
        p[0] = f2h(v[0]);   p[64] = f2h(v[1]);
        p[128] = f2h(v[2]); p[192] = f2h(v[3]);
      } else {
        *(ushort4*)(Vt + (((size_t)bb * 16 + h) * 64 + hd) * 2048 + nq0) =
            make_ushort4(f2h(v[0]), f2h(v[1]), f2h(v[2]), f2h(v[3]));
      }
    }
  }
}

// ---------------------------------------------------------------------------
// Kernel 2: flash attention.  TWO KV-tiles per barrier (16 segments x 2
// tiles).  ROUND-10 FIX: plane size is 64*32 = 2048 ushorts (round 9 wrongly
// declared 64*32/2, halving the plane -> staging overflow -> corruption).
// Per-tile compute byte-identical to verified round-8 (swapped QK^T, permlane
// repack, ones-column lsum, pkrtz).  LDS: K 32KB + V 32KB + Om 40KB = 104KB.
// ---------------------------------------------------------------------------
__global__ __launch_bounds__(1024, 4) void attn_kernel(
    const unsigned short* __restrict__ Qb, const unsigned short* __restrict__ Kb,
    const unsigned short* __restrict__ Vt, unsigned short* __restrict__ Ob) {
  __shared__ __align__(16) unsigned short K_sh[2][2][2][64 * 32];  // [buf][tile][plane][2048]
  __shared__ __align__(16) unsigned short V_sh[2][2][2][64 * 32];
  __shared__ __align__(16) f32x4 Om[8][5][64];   // 40 KB merge (ni 0..3 + ones)
  const int bh = blockIdx.y, q0 = blockIdx.x * 256;
  const size_t base = (size_t)bh * (2048 * 64);
  const unsigned short* Qp = Qb + base;
  const unsigned short* Kp = Kb + base;
  const unsigned short* Vp = Vt + base;  // [64][2048]
  const int tid = threadIdx.x, lane = tid & 63, wave = tid >> 6;  // 0..15
  const int lm = lane & 15, lg = lane >> 4;
  const int r4 = lane >> 2;
  const int sg8 = (((lane & 3) ^ ((r4 >> 1) & 3)) * 8);
  const int lgx = (lg ^ ((lm >> 1) & 3)) * 8;

  const int qg = wave >> 1;      // 0..7 : q-group (32 rows)
  const int khalf = wave & 1;    // 0/1  : kv half within each 64-tile

  f16x8 vones;
#pragma unroll
  for (int j = 0; j < 8; ++j) vones[j] = (_Float16)1.0f;

  f16x8 qf[2][2];
#pragma unroll
  for (int mi = 0; mi < 2; ++mi)
#pragma unroll
    for (int kc = 0; kc < 2; ++kc)
      qf[mi][kc] = *(const f16x8*)(Qp +
          (size_t)(q0 + qg * 32 + mi * 16 + lm) * 64 + kc * 32 + lg * 8);

  f32x4 o[2][4] = {};
  f32x4 o_ones[2] = {};

  // staging roles: 16 waves, 1 GLOAD per tile (8 K-chunks + 8 V-chunks of 1KB)
  const bool isV = wave >= 8;
  const int sw = wave & 7;
  const int plane = sw & 1;
  const int chunk = sw >> 1;     // 0..3 : 16-row group within the plane

#define STAGE1(kt_, b_, t_)                                                   \
  do {                                                                        \
    if (!isV) {                                                               \
      GLOAD_LDS16(Kp + (size_t)((kt_) * 64 + chunk * 16 + r4) * 64 +          \
                      plane * 32 + sg8,                                       \
                  &K_sh[b_][t_][plane][chunk * 512]);                         \
    } else {                                                                  \
      GLOAD_LDS16(Vp + (size_t)(chunk * 16 + r4) * 2048 +                     \
                      (kt_) * 64 + plane * 32 + sg8,                          \
                  &V_sh[b_][t_][plane][chunk * 512]);                         \
    }                                                                         \
  } while (0)

#define STAGE2(seg_, b_)                                                      \
  do { STAGE1(2 * (seg_), b_, 0); STAGE1(2 * (seg_) + 1, b_, 1); } while (0)

  // per-tile compute: swapped QK^T -> exp2+pkrtz -> permlane repack -> PV
#define TILE_COMPUTE(cur_, t_)                                                \
  do {                                                                        \
    f32x4 s[2][2] = {};                                                       \
    __builtin_amdgcn_s_setprio(1);                                            \
    _Pragma("unroll")                                                         \
    for (int kc = 0; kc < 2; ++kc) {                                          \
      _Pragma("unroll")                                                       \
      for (int ni = 0; ni < 2; ++ni) {                                        \
        const f16x8 kf = *(const f16x8*)                                      \
            &K_sh[cur_][t_][kc][(khalf * 32 + ni * 16 + lm) * 32 + lgx];      \
        s[0][ni] = __builtin_amdgcn_mfma_f32_16x16x32_f16(                    \
            kf, qf[0][kc], s[0][ni], 0, 0, 0);                                \
        s[1][ni] = __builtin_amdgcn_mfma_f32_16x16x32_f16(                    \
            kf, qf[1][kc], s[1][ni], 0, 0, 0);                                \
      }                                                                       \
    }                                                                         \
    __builtin_amdgcn_s_setprio(0);                                            \
    unsigned int Wp_[2][2][2];                                                \
    _Pragma("unroll")                                                         \
    for (int mi = 0; mi < 2; ++mi) {                                          \
      _Pragma("unroll")                                                       \
      for (int ni = 0; ni < 2; ++ni) {                                        \
        const float p0 = EXP2(s[mi][ni][0]), p1 = EXP2(s[mi][ni][1]);         \
        const float p2 = EXP2(s[mi][ni][2]), p3 = EXP2(s[mi][ni][3]);         \
        Wp_[mi][ni][0] = pkrtz(p0, p1);                                       \
        Wp_[mi][ni][1] = pkrtz(p2, p3);                                       \
      }                                                                       \
    }                                                                         \
    f16x8 vb[4];                                                              \
    _Pragma("unroll")                                                         \
    for (int ni = 0; ni < 4; ++ni)                                            \
      vb[ni] = *(const f16x8*)                                                \
          &V_sh[cur_][t_][khalf][(ni * 16 + lm) * 32 + lgx];                  \
    _Pragma("unroll")                                                         \
    for (int mi = 0; mi < 2; ++mi) {                                          \
      auto t0 = __builtin_amdgcn_permlane32_swap(Wp_[mi][0][0], Wp_[mi][1][0],\
                                                 false, false);               \
      auto u0 = __builtin_amdgcn_permlane16_swap(t0[0], t0[1], false, false); \
      auto t1 = __builtin_amdgcn_permlane32_swap(Wp_[mi][0][1], Wp_[mi][1][1],\
                                                 false, false);               \
      auto u1 = __builtin_amdgcn_permlane16_swap(t1[0], t1[1], false, false); \
      union { unsigned int u[4]; f16x8 v; } pa;                               \
      pa.u[0] = u0[0];                                                        \
      pa.u[1] = u1[0];                                                        \
      pa.u[2] = u0[1];                                                        \
      pa.u[3] = u1[1];                                                        \
      __builtin_amdgcn_s_setprio(1);                                          \
      _Pragma("unroll")                                                       \
      for (int ni = 0; ni < 4; ++ni)                                          \
        o[mi][ni] = __builtin_amdgcn_mfma_f32_16x16x32_f16(                   \
            pa.v, vb[ni], o[mi][ni], 0, 0, 0);                                \
      o_ones[mi] = __builtin_amdgcn_mfma_f32_16x16x32_f16(                    \
          pa.v, vones, o_ones[mi], 0, 0, 0);                                  \
      __builtin_amdgcn_s_setprio(0);                                          \
    }                                                                         \
  } while (0)

  STAGE2(0, 0);

  for (int seg = 0; seg < 16; ++seg) {
    const int cur = seg & 1;
    __syncthreads();
    if (seg < 15) STAGE2(seg + 1, cur ^ 1);
    TILE_COMPUTE(cur, 0);
    TILE_COMPUTE(cur, 1);
  }
#undef STAGE1
#undef STAGE2
#undef TILE_COMPUTE

  // ---- merge the two kv-halves via dedicated LDS, one mi-pass at a time ----
  const int b = bh >> 4, h = bh & 15;
#pragma unroll
  for (int mi = 0; mi < 2; ++mi) {
    __syncthreads();
    if (khalf == 1) {
#pragma unroll
      for (int ni = 0; ni < 4; ++ni) Om[qg][ni][lane] = o[mi][ni];
      Om[qg][4][lane] = o_ones[mi];
    }
    __syncthreads();
    if (khalf == 0) {
#pragma unroll
      for (int ni = 0; ni < 4; ++ni) {
        const f32x4 t = Om[qg][ni][lane];
        o[mi][ni][0] += t[0]; o[mi][ni][1] += t[1];
        o[mi][ni][2] += t[2]; o[mi][ni][3] += t[3];
      }
      const f32x4 t4 = Om[qg][4][lane];
#pragma unroll
      for (int r = 0; r < 4; ++r) {
        const float inv = 1.0f / (o_ones[mi][r] + t4[r]);
        const int nq = q0 + qg * 32 + mi * 16 + lg * 4 + r;
        unsigned short* p = Ob + ((size_t)(b * 2048 + nq) * 16 + h) * 64 + lm;
        p[0] = f2h(o[mi][0][r] * inv);
        p[16] = f2h(o[mi][1][r] * inv);
        p[32] = f2h(o[mi][2][r] * inv);
        p[48] = f2h(o[mi][3][r] * inv);
      }
    }
  }
}

// ---------------------------------------------------------------------------
// Kernel 3: output projection, BK=32, 64x128 tile, fp16 MFMA.
// (dbuf async staging + XOR swizzle; launch_bounds (256,4))
// ---------------------------------------------------------------------------
__global__ __launch_bounds__(256, 4) void proj_gemm(
    const unsigned short* __restrict__ A, const unsigned short* __restrict__ Wb,
    const float* __restrict__ bias, float* __restrict__ Out) {
  __shared__ __align__(16) unsigned short A_sh[2][64 * 32];
  __shared__ __align__(16) unsigned short B_sh[2][128 * 32];
  const int n0 = blockIdx.x * 128, m0 = blockIdx.y * 64;
  const int tid = threadIdx.x, lane = tid & 63, wave = tid >> 6;
  const int wr = wave >> 1, wc = wave & 1, lm = lane & 15, lg = lane >> 4;
  const int r4 = lane >> 2;
  const int sg8 = (((lane & 3) ^ ((r4 >> 1) & 3)) * 8);
  const int lgx = (lg ^ ((lm >> 1) & 3)) * 8;

  f32x4 acc[2][4] = {};

#define PSTAGE(k0_, b_)                                                       \
  do {                                                                        \
    {                                                                         \
      const int row = wave * 16 + r4;                                         \
      GLOAD_LDS16(A + (size_t)(m0 + row) * 1024 + (k0_) + sg8,                \
                  &A_sh[b_][wave * 512]);                                     \
    }                                                                         \
    _Pragma("unroll")                                                         \
    for (int j = 0; j < 2; ++j) {                                             \
      const int chunk = wave * 2 + j;                                         \
      const int row = chunk * 16 + r4;                                        \
      GLOAD_LDS16(Wb + (size_t)(n0 + row) * 1024 + (k0_) + sg8,               \
                  &B_sh[b_][chunk * 512]);                                    \
    }                                                                         \
  } while (0)

  PSTAGE(0, 0);

  for (int it = 0; it < 32; ++it) {
    const int cur = it & 1;
    __syncthreads();
    if (it < 31) PSTAGE((it + 1) * 32, cur ^ 1);

    f16x8 af[2], bfr[4];
#pragma unroll
    for (int mi = 0; mi < 2; ++mi)
      af[mi] = *(const f16x8*)&A_sh[cur][(wr * 32 + mi * 16 + lm) * 32 + lgx];
#pragma unroll
    for (int ni = 0; ni < 4; ++ni)
      bfr[ni] = *(const f16x8*)&B_sh[cur][(wc * 64 + ni * 16 + lm) * 32 + lgx];
#pragma unroll
    for (int mi = 0; mi < 2; ++mi)
#pragma unroll
      for (int ni = 0; ni < 4; ++ni)
        acc[mi][ni] = __builtin_amdgcn_mfma_f32_16x16x32_f16(
            af[mi], bfr[ni], acc[mi][ni], 0, 0, 0);
  }
#undef PSTAGE

#pragma unroll
  for (int mi = 0; mi < 2; ++mi)
#pragma unroll
    for (int ni = 0; ni < 4; ++ni) {
      const int gn = n0 + wc * 64 + ni * 16 + lm;
      const float bv = bias[gn];
#pragma unroll
      for (int r = 0; r < 4; ++r) {
        const int gm = m0 + wr * 32 + mi * 16 + lg * 4 + r;
        Out[(size_t)gm * 1024 + gn] = acc[mi][ni][r] + bv;
      }
    }
}

extern "C" void kernel_launch(void* const* d_in, const int* in_sizes, int n_in,
                              void* d_out, int out_size, void* d_ws, size_t ws_size,
                              hipStream_t stream) {
  const float* x      = (const float*)d_in[0];
  const float* W_qkv  = (const float*)d_in[1];
  const float* b_qkv  = (const float*)d_in[2];
  const float* W_proj = (const float*)d_in[3];
  const float* b_proj = (const float*)d_in[4];
  float* out = (float*)d_out;

  unsigned short* Qb  = (unsigned short*)d_ws;
  unsigned short* Kb  = Qb + 4194304;
  unsigned short* Vt  = Kb + 4194304;
  unsigned short* Ao  = Vt + 4194304;
  unsigned short* Xb  = Ao + 4194304;
  unsigned short* Wqb = Xb + 4194304;
  unsigned short* Wpb = Wqb + 3145728;

  cvt_all<<<8192, 256, 0, stream>>>(x, W_qkv, W_proj, Xb, Wqb, Wpb);
  qkv_gemm<<<dim3(24, 32), 256, 0, stream>>>(Xb, Wqb, b_qkv, Qb, Kb, Vt);
  attn_kernel<<<dim3(8, 32), 1024, 0, stream>>>(Qb, Kb, Vt, Ao);
  proj_gemm<<<dim3(8, 64), 256, 0, stream>>>(Ao, Wpb, b_proj, out);
}

// Round 11
// 175.592 us; speedup vs baseline: 1.1393x; 1.0208x over previous
//
#include <hip/hip_runtime.h>

typedef _Float16 f16x8 __attribute__((ext_vector_type(8)));
typedef __attribute__((ext_vector_type(4))) float f32x4;

// fp32 -> fp16 (RNE) bit pattern
static __device__ __forceinline__ unsigned short f2h(float f) {
  return __builtin_bit_cast(unsigned short, (_Float16)f);
}

// pack two fp32 -> one dword of two fp16
static __device__ __forceinline__ unsigned int pk2(float a, float b) {
  return (unsigned int)f2h(a) | ((unsigned int)f2h(b) << 16);
}

// packed RTZ convert (1 VALU op vs 3); numerator/denominator bias cancels
#if __has_builtin(__builtin_amdgcn_cvt_pkrtz)
static __device__ __forceinline__ unsigned int pkrtz(float a, float b) {
  return __builtin_bit_cast(unsigned int, __builtin_amdgcn_cvt_pkrtz(a, b));
}
#else
#define pkrtz pk2
#endif

// raw v_exp_f32 (inputs bounded; fp16 margin absorbs the ~1ulp gap vs libm)
#if __has_builtin(__builtin_amdgcn_exp2f)
#define EXP2(x) __builtin_amdgcn_exp2f(x)
#else
#define EXP2(x) exp2f(x)
#endif

// async global->LDS, 16 B per lane; LDS dst = wave-uniform base + lane*16.
#define GLOAD_LDS16(gp, lp)                                          \
  __builtin_amdgcn_global_load_lds(                                  \
      (const __attribute__((address_space(1))) unsigned int*)(gp),   \
      (__attribute__((address_space(3))) unsigned int*)(lp), 16, 0, 0)

// ---------------------------------------------------------------------------
// Kernel 0: fp32 -> fp16 conversion for X, W_qkv, W_proj (one launch).
// (pure streaming, no reuse -> no XCD swizzle: T1 is null on streaming ops)
// ---------------------------------------------------------------------------
__global__ __launch_bounds__(256) void cvt_all(
    const float* __restrict__ X, const float* __restrict__ Wq,
    const float* __restrict__ Wp, unsigned short* __restrict__ Xb,
    unsigned short* __restrict__ Wqb, unsigned short* __restrict__ Wpb) {
  const int i = blockIdx.x * 256 + threadIdx.x;
  const float4* src;
  unsigned short* dst;
  int off;
  if (i < 1048576) {
    src = (const float4*)X; dst = Xb; off = i;
  } else if (i < 1835008) {
    src = (const float4*)Wq; dst = Wqb; off = i - 1048576;
  } else {
    src = (const float4*)Wp; dst = Wpb; off = i - 1835008;
  }
  const float4 v = src[off];
  *(ushort4*)(dst + (size_t)off * 4) =
      make_ushort4(f2h(v.x), f2h(v.y), f2h(v.z), f2h(v.w));
}

// ---------------------------------------------------------------------------
// Kernel 1: QKV projection.  256 threads / 4 waves (2x2 wave grid), each wave
// owns a 64x64 sub-tile (acc[4][4]) of the 128x128 tile.  8 ds_read_b128 feed
// 16 MFMA.  BK=32, glds dbuf (1 barrier/iter) + XOR column-group swizzle.
// NEW: XCD-aware block swizzle (T1) -- 768 blocks = 8 XCDs x 96; each XCD
// gets a contiguous 12(n) x 8(m) tile region (working set ~5MB vs scattered)
// so A/B panel re-reads become same-XCD L2 hits.  Bijective: 768=8*96=8*12*8.
// Q pre-scaled by log2(e)/8.
//   Q,K: [B,H,2048,64] fp16     V: transposed [B,H,64,2048] fp16
// ---------------------------------------------------------------------------
__global__ __launch_bounds__(256, 4) void qkv_gemm(
    const unsigned short* __restrict__ Xb, const unsigned short* __restrict__ Wb,
    const float* __restrict__ bias, unsigned short* __restrict__ Qb,
    unsigned short* __restrict__ Kb, unsigned short* __restrict__ Vt) {
  __shared__ __align__(16) unsigned short A_sh[2][128 * 32];
  __shared__ __align__(16) unsigned short B_sh[2][128 * 32];
  // T1 XCD swizzle: linear id -> (xcd, slot) -> 12x8 sub-grid per XCD
  const int bid = blockIdx.y * 24 + blockIdx.x;
  const int xcd = bid & 7, slot = bid >> 3;            // slot 0..95
  const int bx = (xcd & 1) * 12 + (slot % 12);         // 0..23
  const int by = (xcd >> 1) * 8 + (slot / 12);         // 0..31
  const int n0 = bx * 128, m0 = by * 128;
  const int tid = threadIdx.x, lane = tid & 63, wave = tid >> 6;  // 0..3
  const int wr = wave >> 1, wc = wave & 1;   // 2x2 wave grid, 64x64 each
  const int lm = lane & 15, lg = lane >> 4;
  const int r4 = lane >> 2;                              // staging row in chunk
  const int sg8 = (((lane & 3) ^ ((r4 >> 1) & 3)) * 8);  // swizzled src colgrp
  const int lgx = (lg ^ ((lm >> 1) & 3)) * 8;            // swizzled read colgrp

  f32x4 acc[4][4] = {};

#define QSTAGE(k0_, b_)                                                       \
  do {                                                                        \
    _Pragma("unroll")                                                         \
    for (int j = 0; j < 2; ++j) {                                             \
      const int chunk = wave * 2 + j;                                         \
      const int row = chunk * 16 + r4;                                        \
      GLOAD_LDS16(Xb + (size_t)(m0 + row) * 1024 + (k0_) + sg8,               \
                  &A_sh[b_][chunk * 512]);                                    \
      GLOAD_LDS16(Wb + (size_t)(n0 + row) * 1024 + (k0_) + sg8,               \
                  &B_sh[b_][chunk * 512]);                                    \
    }                                                                         \
  } while (0)

  QSTAGE(0, 0);

  for (int it = 0; it < 32; ++it) {
    const int cur = it & 1;
    __syncthreads();  // buf[cur] ready; buf[cur^1] free
    if (it < 31) QSTAGE((it + 1) * 32, cur ^ 1);  // fly during compute

    f16x8 af[4], bfr[4];
#pragma unroll
    for (int mi = 0; mi < 4; ++mi)
      af[mi] = *(const f16x8*)&A_sh[cur][(wr * 64 + mi * 16 + lm) * 32 + lgx];
#pragma unroll
    for (int ni = 0; ni < 4; ++ni)
      bfr[ni] = *(const f16x8*)&B_sh[cur][(wc * 64 + ni * 16 + lm) * 32 + lgx];
    __builtin_amdgcn_s_setprio(1);
#pragma unroll
    for (int mi = 0; mi < 4; ++mi)
#pragma unroll
      for (int ni = 0; ni < 4; ++ni)
        acc[mi][ni] = __builtin_amdgcn_mfma_f32_16x16x32_f16(
            af[mi], bfr[ni], acc[mi][ni], 0, 0, 0);
    __builtin_amdgcn_s_setprio(0);
  }
#undef QSTAGE

  const float qscale = 0.18033688011112042f;  // log2(e)/8  (folded attn scale)
#pragma unroll
  for (int mi = 0; mi < 4; ++mi) {
#pragma unroll
    for (int ni = 0; ni < 4; ++ni) {
      const int gn = n0 + wc * 64 + ni * 16 + lm;
      const float bv = bias[gn];
      const int which = gn >> 10;
      const int h = (gn >> 6) & 15;
      const int hd = gn & 63;
      float v[4];
#pragma unroll
      for (int r = 0; r < 4; ++r) v[r] = acc[mi][ni][r] + bv;
      const int gm0 = m0 + wr * 64 + mi * 16 + lg * 4;
      const int bb = gm0 >> 11;
      const int nq0 = gm0 & 2047;
      if (which == 0) {
        unsigned short* p = Qb + (((size_t)bb * 16 + h) * 2048 + nq0) * 64 + hd;
        p[0] = f2h(v[0] * qscale);   p[64] = f2h(v[1] * qscale);
        p[128] = f2h(v[2] * qscale); p[192] = f2h(v[3] * qscale);
      } else if (which == 1) {
        unsigned short* p = Kb + (((size_t)bb * 16 + h) * 2048 + nq0) * 64 + hd;
        p[0] = f2h(v[0]);   p[64] = f2h(v[1]);
        p[128] = f2h(v[2]); p[192] = f2h(v[3]);
      } else {
        *(ushort4*)(Vt + (((size_t)bb * 16 + h) * 64 + hd) * 2048 + nq0) =
            make_ushort4(f2h(v[0]), f2h(v[1]), f2h(v[2]), f2h(v[3]));
      }
    }
  }
}

// ---------------------------------------------------------------------------
// Kernel 2: flash attention.  TWO KV-tiles per barrier (16 segments x 2
// tiles), verified round 10.  NEW: XCD-aware block swizzle (T1) -- 256 blocks
// = 8 XCDs x 32; each XCD handles 4 heads' full q-range, so each head's
// K/V (512KB) is read by 8 same-XCD blocks -> L2-resident (FETCH was 2.9x
// unique).  Bijective: bh = xcd*4 + slot/8, q0 = (slot&7)*256.
// LDS: K 32KB + V 32KB + Om 40KB = 104KB.
// ---------------------------------------------------------------------------
__global__ __launch_bounds__(1024, 4) void attn_kernel(
    const unsigned short* __restrict__ Qb, const unsigned short* __restrict__ Kb,
    const unsigned short* __restrict__ Vt, unsigned short* __restrict__ Ob) {
  __shared__ __align__(16) unsigned short K_sh[2][2][2][64 * 32];  // [buf][tile][plane][2048]
  __shared__ __align__(16) unsigned short V_sh[2][2][2][64 * 32];
  __shared__ __align__(16) f32x4 Om[8][5][64];   // 40 KB merge (ni 0..3 + ones)
  // T1 XCD swizzle
  const int bid = blockIdx.y * 8 + blockIdx.x;
  const int xcd = bid & 7, slot = bid >> 3;      // slot 0..31
  const int bh = xcd * 4 + (slot >> 3);          // 0..31
  const int q0 = (slot & 7) * 256;
  const size_t base = (size_t)bh * (2048 * 64);
  const unsigned short* Qp = Qb + base;
  const unsigned short* Kp = Kb + base;
  const unsigned short* Vp = Vt + base;  // [64][2048]
  const int tid = threadIdx.x, lane = tid & 63, wave = tid >> 6;  // 0..15
  const int lm = lane & 15, lg = lane >> 4;
  const int r4 = lane >> 2;
  const int sg8 = (((lane & 3) ^ ((r4 >> 1) & 3)) * 8);
  const int lgx = (lg ^ ((lm >> 1) & 3)) * 8;

  const int qg = wave >> 1;      // 0..7 : q-group (32 rows)
  const int khalf = wave & 1;    // 0/1  : kv half within each 64-tile

  f16x8 vones;
#pragma unroll
  for (int j = 0; j < 8; ++j) vones[j] = (_Float16)1.0f;

  f16x8 qf[2][2];
#pragma unroll
  for (int mi = 0; mi < 2; ++mi)
#pragma unroll
    for (int kc = 0; kc < 2; ++kc)
      qf[mi][kc] = *(const f16x8*)(Qp +
          (size_t)(q0 + qg * 32 + mi * 16 + lm) * 64 + kc * 32 + lg * 8);

  f32x4 o[2][4] = {};
  f32x4 o_ones[2] = {};

  // staging roles: 16 waves, 1 GLOAD per tile (8 K-chunks + 8 V-chunks of 1KB)
  const bool isV = wave >= 8;
  const int sw = wave & 7;
  const int plane = sw & 1;
  const int chunk = sw >> 1;     // 0..3 : 16-row group within the plane

#define STAGE1(kt_, b_, t_)                                                   \
  do {                                                                        \
    if (!isV) {                                                               \
      GLOAD_LDS16(Kp + (size_t)((kt_) * 64 + chunk * 16 + r4) * 64 +          \
                      plane * 32 + sg8,                                       \
                  &K_sh[b_][t_][plane][chunk * 512]);                         \
    } else {                                                                  \
      GLOAD_LDS16(Vp + (size_t)(chunk * 16 + r4) * 2048 +                     \
                      (kt_) * 64 + plane * 32 + sg8,                          \
                  &V_sh[b_][t_][plane][chunk * 512]);                         \
    }                                                                         \
  } while (0)

#define STAGE2(seg_, b_)                                                      \
  do { STAGE1(2 * (seg_), b_, 0); STAGE1(2 * (seg_) + 1, b_, 1); } while (0)

  // per-tile compute: swapped QK^T -> exp2+pkrtz -> permlane repack -> PV
#define TILE_COMPUTE(cur_, t_)                                                \
  do {                                                                        \
    f32x4 s[2][2] = {};                                                       \
    __builtin_amdgcn_s_setprio(1);                                            \
    _Pragma("unroll")                                                         \
    for (int kc = 0; kc < 2; ++kc) {                                          \
      _Pragma("unroll")                                                       \
      for (int ni = 0; ni < 2; ++ni) {                                        \
        const f16x8 kf = *(const f16x8*)                                      \
            &K_sh[cur_][t_][kc][(khalf * 32 + ni * 16 + lm) * 32 + lgx];      \
        s[0][ni] = __builtin_amdgcn_mfma_f32_16x16x32_f16(                    \
            kf, qf[0][kc], s[0][ni], 0, 0, 0);                                \
        s[1][ni] = __builtin_amdgcn_mfma_f32_16x16x32_f16(                    \
            kf, qf[1][kc], s[1][ni], 0, 0, 0);                                \
      }                                                                       \
    }                                                                         \
    __builtin_amdgcn_s_setprio(0);                                            \
    unsigned int Wp_[2][2][2];                                                \
    _Pragma("unroll")                                                         \
    for (int mi = 0; mi < 2; ++mi) {                                          \
      _Pragma("unroll")                                                       \
      for (int ni = 0; ni < 2; ++ni) {                                        \
        const float p0 = EXP2(s[mi][ni][0]), p1 = EXP2(s[mi][ni][1]);         \
        const float p2 = EXP2(s[mi][ni][2]), p3 = EXP2(s[mi][ni][3]);         \
        Wp_[mi][ni][0] = pkrtz(p0, p1);                                       \
        Wp_[mi][ni][1] = pkrtz(p2, p3);                                       \
      }                                                                       \
    }                                                                         \
    f16x8 vb[4];                                                              \
    _Pragma("unroll")                                                         \
    for (int ni = 0; ni < 4; ++ni)                                            \
      vb[ni] = *(const f16x8*)                                                \
          &V_sh[cur_][t_][khalf][(ni * 16 + lm) * 32 + lgx];                  \
    _Pragma("unroll")                                                         \
    for (int mi = 0; mi < 2; ++mi) {                                          \
      auto t0 = __builtin_amdgcn_permlane32_swap(Wp_[mi][0][0], Wp_[mi][1][0],\
                                                 false, false);               \
      auto u0 = __builtin_amdgcn_permlane16_swap(t0[0], t0[1], false, false); \
      auto t1 = __builtin_amdgcn_permlane32_swap(Wp_[mi][0][1], Wp_[mi][1][1],\
                                                 false, false);               \
      auto u1 = __builtin_amdgcn_permlane16_swap(t1[0], t1[1], false, false); \
      union { unsigned int u[4]; f16x8 v; } pa;                               \
      pa.u[0] = u0[0];                                                        \
      pa.u[1] = u1[0];                                                        \
      pa.u[2] = u0[1];                                                        \
      pa.u[3] = u1[1];                                                        \
      __builtin_amdgcn_s_setprio(1);                                          \
      _Pragma("unroll")                                                       \
      for (int ni = 0; ni < 4; ++ni)                                          \
        o[mi][ni] = __builtin_amdgcn_mfma_f32_16x16x32_f16(                   \
            pa.v, vb[ni], o[mi][ni], 0, 0, 0);                                \
      o_ones[mi] = __builtin_amdgcn_mfma_f32_16x16x32_f16(                    \
          pa.v, vones, o_ones[mi], 0, 0, 0);                                  \
      __builtin_amdgcn_s_setprio(0);                                          \
    }                                                                         \
  } while (0)

  STAGE2(0, 0);

  for (int seg = 0; seg < 16; ++seg) {
    const int cur = seg & 1;
    __syncthreads();
    if (seg < 15) STAGE2(seg + 1, cur ^ 1);
    TILE_COMPUTE(cur, 0);
    TILE_COMPUTE(cur, 1);
  }
#undef STAGE1
#undef STAGE2
#undef TILE_COMPUTE

  // ---- merge the two kv-halves via dedicated LDS, one mi-pass at a time ----
  const int b = bh >> 4, h = bh & 15;
#pragma unroll
  for (int mi = 0; mi < 2; ++mi) {
    __syncthreads();
    if (khalf == 1) {
#pragma unroll
      for (int ni = 0; ni < 4; ++ni) Om[qg][ni][lane] = o[mi][ni];
      Om[qg][4][lane] = o_ones[mi];
    }
    __syncthreads();
    if (khalf == 0) {
#pragma unroll
      for (int ni = 0; ni < 4; ++ni) {
        const f32x4 t = Om[qg][ni][lane];
        o[mi][ni][0] += t[0]; o[mi][ni][1] += t[1];
        o[mi][ni][2] += t[2]; o[mi][ni][3] += t[3];
      }
      const f32x4 t4 = Om[qg][4][lane];
#pragma unroll
      for (int r = 0; r < 4; ++r) {
        const float inv = 1.0f / (o_ones[mi][r] + t4[r]);
        const int nq = q0 + qg * 32 + mi * 16 + lg * 4 + r;
        unsigned short* p = Ob + ((size_t)(b * 2048 + nq) * 16 + h) * 64 + lm;
        p[0] = f2h(o[mi][0][r] * inv);
        p[16] = f2h(o[mi][1][r] * inv);
        p[32] = f2h(o[mi][2][r] * inv);
        p[48] = f2h(o[mi][3][r] * inv);
      }
    }
  }
}

// ---------------------------------------------------------------------------
// Kernel 3: output projection, BK=32, 64x128 tile, fp16 MFMA.
// (dbuf async staging + XOR swizzle; launch_bounds (256,4))
// NEW: XCD-aware block swizzle (T1) -- 512 blocks = 8 XCDs x 64; each XCD a
// 4(n) x 16(m) region (working set ~3MB, L2-fits).  Bijective: 512=8*4*16.
// ---------------------------------------------------------------------------
__global__ __launch_bounds__(256, 4) void proj_gemm(
    const unsigned short* __restrict__ A, const unsigned short* __restrict__ Wb,
    const float* __restrict__ bias, float* __restrict__ Out) {
  __shared__ __align__(16) unsigned short A_sh[2][64 * 32];
  __shared__ __align__(16) unsigned short B_sh[2][128 * 32];
  // T1 XCD swizzle
  const int bid = blockIdx.y * 8 + blockIdx.x;
  const int xcd = bid & 7, slot = bid >> 3;        // slot 0..63
  const int bx = (xcd & 1) * 4 + (slot & 3);       // 0..7
  const int by = (xcd >> 1) * 16 + (slot >> 2);    // 0..63
  const int n0 = bx * 128, m0 = by * 64;
  const int tid = threadIdx.x, lane = tid & 63, wave = tid >> 6;
  const int wr = wave >> 1, wc = wave & 1, lm = lane & 15, lg = lane >> 4;
  const int r4 = lane >> 2;
  const int sg8 = (((lane & 3) ^ ((r4 >> 1) & 3)) * 8);
  const int lgx = (lg ^ ((lm >> 1) & 3)) * 8;

  f32x4 acc[2][4] = {};

#define PSTAGE(k0_, b_)                                                       \
  do {                                                                        \
    {                                                                         \
      const int row = wave * 16 + r4;                                         \
      GLOAD_LDS16(A + (size_t)(m0 + row) * 1024 + (k0_) + sg8,                \
                  &A_sh[b_][wave * 512]);                                     \
    }                                                                         \
    _Pragma("unroll")                                                         \
    for (int j = 0; j < 2; ++j) {                                             \
      const int chunk = wave * 2 + j;                                         \
      const int row = chunk * 16 + r4;                                        \
      GLOAD_LDS16(Wb + (size_t)(n0 + row) * 1024 + (k0_) + sg8,               \
                  &B_sh[b_][chunk * 512]);                                    \
    }                                                                         \
  } while (0)

  PSTAGE(0, 0);

  for (int it = 0; it < 32; ++it) {
    const int cur = it & 1;
    __syncthreads();
    if (it < 31) PSTAGE((it + 1) * 32, cur ^ 1);

    f16x8 af[2], bfr[4];
#pragma unroll
    for (int mi = 0; mi < 2; ++mi)
      af[mi] = *(const f16x8*)&A_sh[cur][(wr * 32 + mi * 16 + lm) * 32 + lgx];
#pragma unroll
    for (int ni = 0; ni < 4; ++ni)
      bfr[ni] = *(const f16x8*)&B_sh[cur][(wc * 64 + ni * 16 + lm) * 32 + lgx];
#pragma unroll
    for (int mi = 0; mi < 2; ++mi)
#pragma unroll
      for (int ni = 0; ni < 4; ++ni)
        acc[mi][ni] = __builtin_amdgcn_mfma_f32_16x16x32_f16(
            af[mi], bfr[ni], acc[mi][ni], 0, 0, 0);
  }
#undef PSTAGE

#pragma unroll
  for (int mi = 0; mi < 2; ++mi)
#pragma unroll
    for (int ni = 0; ni < 4; ++ni) {
      const int gn = n0 + wc * 64 + ni * 16 + lm;
      const float bv = bias[gn];
#pragma unroll
      for (int r = 0; r < 4; ++r) {
        const int gm = m0 + wr * 32 + mi * 16 + lg * 4 + r;
        Out[(size_t)gm * 1024 + gn] = acc[mi][ni][r] + bv;
      }
    }
}

extern "C" void kernel_launch(void* const* d_in, const int* in_sizes, int n_in,
                              void* d_out, int out_size, void* d_ws, size_t ws_size,
                              hipStream_t stream) {
  const float* x      = (const float*)d_in[0];
  const float* W_qkv  = (const float*)d_in[1];
  const float* b_qkv  = (const float*)d_in[2];
  const float* W_proj = (const float*)d_in[3];
  const float* b_proj = (const float*)d_in[4];
  float* out = (float*)d_out;

  unsigned short* Qb  = (unsigned short*)d_ws;
  unsigned short* Kb  = Qb + 4194304;
  unsigned short* Vt  = Kb + 4194304;
  unsigned short* Ao  = Vt + 4194304;
  unsigned short* Xb  = Ao + 4194304;
  unsigned short* Wqb = Xb + 4194304;
  unsigned short* Wpb = Wqb + 3145728;

  cvt_all<<<8192, 256, 0, stream>>>(x, W_qkv, W_proj, Xb, Wqb, Wpb);
  qkv_gemm<<<dim3(24, 32), 256, 0, stream>>>(Xb, Wqb, b_qkv, Qb, Kb, Vt);
  attn_kernel<<<dim3(8, 32), 1024, 0, stream>>>(Qb, Kb, Vt, Ao);
  proj_gemm<<<dim3(8, 64), 256, 0, stream>>>(Ao, Wpb, b_proj, out);
}